// Round 1
// baseline (1148.744 us; speedup 1.0000x reference)
//
#include <hip/hip_runtime.h>
#include <math.h>

#define N_NODES 100000
#define N_EDGES 1600000
#define N_GRAPHS 64
#define EMB 128
#define HID 64

// ---------------- CSR build ----------------

__global__ void deg_kernel(const int* __restrict__ dst, int* __restrict__ deg, int e) {
    int i = blockIdx.x * 256 + threadIdx.x;
    if (i < e) atomicAdd(&deg[dst[i]], 1);
}

// phase 1: per-block (256 elems) exclusive scan; write block totals
__global__ void scan_phase1(const int* __restrict__ deg, int* __restrict__ excl,
                            int* __restrict__ blockSums, int n) {
    int i = blockIdx.x * 256 + threadIdx.x;
    int v = (i < n) ? deg[i] : 0;
    int lane = threadIdx.x & 63;
    int wid  = threadIdx.x >> 6;
    int incl = v;
    #pragma unroll
    for (int off = 1; off < 64; off <<= 1) {
        int t = __shfl_up(incl, off);
        if (lane >= off) incl += t;
    }
    __shared__ int wsum[4];
    if (lane == 63) wsum[wid] = incl;
    __syncthreads();
    int woff = 0;
    for (int w = 0; w < wid; ++w) woff += wsum[w];
    if (i < n) excl[i] = woff + incl - v;
    if (threadIdx.x == 255) blockSums[blockIdx.x] = woff + incl;
}

// phase 2: single block (512 threads) scans block sums (nb <= 512)
__global__ void scan_phase2(const int* __restrict__ blockSums, int* __restrict__ blockOffs,
                            int nb, int* __restrict__ total_out) {
    int i = threadIdx.x;
    int v = (i < nb) ? blockSums[i] : 0;
    int lane = i & 63, wid = i >> 6;
    int incl = v;
    #pragma unroll
    for (int off = 1; off < 64; off <<= 1) {
        int t = __shfl_up(incl, off);
        if (lane >= off) incl += t;
    }
    __shared__ int wsum[8];
    if (lane == 63) wsum[wid] = incl;
    __syncthreads();
    int woff = 0;
    for (int w = 0; w < wid; ++w) woff += wsum[w];
    if (i < nb) blockOffs[i] = woff + incl - v;
    if (i == 511) *total_out = woff + incl;
}

// phase 3: add block offsets in place; clone to cursor
__global__ void scan_phase3(int* __restrict__ row_ptr, const int* __restrict__ blockOffs,
                            int* __restrict__ cursor, int n) {
    int i = blockIdx.x * 256 + threadIdx.x;
    if (i < n) {
        int r = row_ptr[i] + blockOffs[blockIdx.x];
        row_ptr[i] = r;
        cursor[i]  = r;
    }
}

__global__ void fill_kernel(const int* __restrict__ src, const int* __restrict__ dst,
                            int* __restrict__ cursor, int* __restrict__ col_idx, int e) {
    int i = blockIdx.x * 256 + threadIdx.x;
    if (i < e) {
        int slot = atomicAdd(&cursor[dst[i]], 1);
        col_idx[slot] = src[i];
    }
}

// ---------------- dense projection: y = h @ W (Din -> 64), no bias ----------------

template <int DIN>
__global__ __launch_bounds__(256) void project_kernel(const float* __restrict__ h,
                                                      const float* __restrict__ W,
                                                      float* __restrict__ y) {
    int wid  = threadIdx.x >> 6;
    int lane = threadIdx.x & 63;
    int node = blockIdx.x * 4 + wid;
    const float4* h4 = reinterpret_cast<const float4*>(h + (size_t)node * DIN);
    float acc = 0.0f;
    #pragma unroll
    for (int k4 = 0; k4 < DIN / 4; ++k4) {
        float4 hv = h4[k4];
        int k = k4 * 4;
        acc = fmaf(hv.x, W[(k + 0) * 64 + lane], acc);
        acc = fmaf(hv.y, W[(k + 1) * 64 + lane], acc);
        acc = fmaf(hv.z, W[(k + 2) * 64 + lane], acc);
        acc = fmaf(hv.w, W[(k + 3) * 64 + lane], acc);
    }
    y[(size_t)node * 64 + lane] = acc;
}

// ---------------- fused layer: gather-sum + bias + relu + GEMM2 + bias (+relu) ----------------

__global__ __launch_bounds__(256) void gin_layer(const float* __restrict__ y,
                                                 const int* __restrict__ row_ptr,
                                                 const int* __restrict__ col_idx,
                                                 const float* __restrict__ b1,
                                                 const float* __restrict__ W2,
                                                 const float* __restrict__ b2,
                                                 float* __restrict__ h, int relu_out) {
    __shared__ float sW2[64 * 64];
    __shared__ float st[4][64];
    for (int idx = threadIdx.x; idx < 64 * 64; idx += 256) sW2[idx] = W2[idx];

    int wid  = threadIdx.x >> 6;
    int lane = threadIdx.x & 63;
    int node = blockIdx.x * 4 + wid;

    int start = row_ptr[node];
    int end   = row_ptr[node + 1];
    float acc = y[(size_t)node * 64 + lane];

    for (int base = start; base < end; base += 64) {
        int cnt = end - base;
        if (cnt > 64) cnt = 64;
        int sidx = (base + lane < end) ? col_idx[base + lane] : 0;
        for (int k = 0; k < cnt; ++k) {
            int s = __shfl(sidx, k);
            acc += y[(size_t)s * 64 + lane];
        }
    }

    float t = fmaxf(acc + b1[lane], 0.0f);
    st[wid][lane] = t;
    __syncthreads();  // covers W2 staging + st

    float u = b2[lane];
    #pragma unroll 16
    for (int k = 0; k < 64; ++k)
        u = fmaf(st[wid][k], sW2[k * 64 + lane], u);
    if (relu_out) u = fmaxf(u, 0.0f);
    h[(size_t)node * 64 + lane] = u;
}

// ---------------- pooling: segment mean (batch is sorted) ----------------

__global__ void pool_kernel(const float* __restrict__ h, const int* __restrict__ batch,
                            float* __restrict__ pool, float* __restrict__ counts, int n) {
    int gwave = (blockIdx.x * blockDim.x + threadIdx.x) >> 6;
    int lane  = threadIdx.x & 63;
    int nwaves = (gridDim.x * blockDim.x) >> 6;
    int chunk = (n + nwaves - 1) / nwaves;
    int s = gwave * chunk;
    int e = min(n, s + chunk);
    if (s >= e) return;
    int cur = batch[s];
    float acc = 0.0f, cnt = 0.0f;
    for (int i = s; i < e; ++i) {
        int g = batch[i];
        if (g != cur) {
            atomicAdd(&pool[cur * 64 + lane], acc);
            if (lane == 0) atomicAdd(&counts[cur], cnt);
            cur = g; acc = 0.0f; cnt = 0.0f;
        }
        acc += h[(size_t)i * 64 + lane];
        cnt += 1.0f;
    }
    atomicAdd(&pool[cur * 64 + lane], acc);
    if (lane == 0) atomicAdd(&counts[cur], cnt);
}

// ---------------- head: pooled @ fc1 + b, @ pred + b, sigmoid ----------------

__global__ void head_kernel(const float* __restrict__ pool, const float* __restrict__ counts,
                            const float* __restrict__ fc1_W, const float* __restrict__ fc1_b,
                            const float* __restrict__ pred_W, const float* __restrict__ pred_b,
                            float* __restrict__ out) {
    int g = blockIdx.x;
    int t = threadIdx.x;  // 64 threads; lanes >= 32 idle for the dot
    float s = 0.0f;
    if (t < 32) {
        float cnt = fmaxf(counts[g], 1.0f);
        float inv = 1.0f / cnt;
        float f = fc1_b[t];
        #pragma unroll
        for (int k = 0; k < 64; ++k)
            f = fmaf(pool[g * 64 + k] * inv, fc1_W[k * 32 + t], f);
        s = f * pred_W[t];
    }
    #pragma unroll
    for (int off = 32; off > 0; off >>= 1) s += __shfl_down(s, off);
    if (t == 0) out[g] = 1.0f / (1.0f + expf(-(s + pred_b[0])));
}

// ---------------- launch ----------------

extern "C" void kernel_launch(void* const* d_in, const int* in_sizes, int n_in,
                              void* d_out, int out_size, void* d_ws, size_t ws_size,
                              hipStream_t stream) {
    const float* x      = (const float*)d_in[0];
    const int*   e_src  = (const int*)d_in[1];               // edge_index[0]
    const int*   e_dst  = ((const int*)d_in[1]) + N_EDGES;   // edge_index[1]
    const int*   batch  = (const int*)d_in[2];
    const float* c1_W1 = (const float*)d_in[3];
    const float* c1_b1 = (const float*)d_in[4];
    const float* c1_W2 = (const float*)d_in[5];
    const float* c1_b2 = (const float*)d_in[6];
    const float* c2_W1 = (const float*)d_in[7];
    const float* c2_b1 = (const float*)d_in[8];
    const float* c2_W2 = (const float*)d_in[9];
    const float* c2_b2 = (const float*)d_in[10];
    const float* c3_W1 = (const float*)d_in[11];
    const float* c3_b1 = (const float*)d_in[12];
    const float* c3_W2 = (const float*)d_in[13];
    const float* c3_b2 = (const float*)d_in[14];
    const float* fc1_W = (const float*)d_in[15];
    const float* fc1_b = (const float*)d_in[16];
    const float* predW = (const float*)d_in[17];
    const float* predb = (const float*)d_in[18];
    float* out = (float*)d_out;

    // workspace carve-up (aligned to 256B)
    char* ws = (char*)d_ws;
    size_t off = 0;
    auto carve = [&](size_t bytes) {
        char* p = ws + off;
        off += (bytes + 255) & ~(size_t)255;
        return p;
    };
    float* y        = (float*)carve((size_t)N_NODES * 64 * 4);
    float* h        = (float*)carve((size_t)N_NODES * 64 * 4);
    int*   deg      = (int*)carve((size_t)N_NODES * 4);
    int*   row_ptr  = (int*)carve(((size_t)N_NODES + 1) * 4);
    int*   cursor   = (int*)carve((size_t)N_NODES * 4);
    int*   col_idx  = (int*)carve((size_t)N_EDGES * 4);
    int*   bsums    = (int*)carve(512 * 4);
    int*   boffs    = (int*)carve(512 * 4);
    float* pool     = (float*)carve(N_GRAPHS * 64 * 4);
    float* counts   = (float*)carve(N_GRAPHS * 4);
    (void)ws_size; (void)n_in; (void)in_sizes; (void)out_size;

    const int SCAN_BLOCKS = (N_NODES + 255) / 256;     // 391
    const int EDGE_BLOCKS = (N_EDGES + 255) / 256;     // 6250
    const int NODE_BLOCKS = N_NODES / 4;               // 25000

    // zero accumulators
    hipMemsetAsync(deg, 0, (size_t)N_NODES * 4, stream);
    hipMemsetAsync(pool, 0, (N_GRAPHS * 64 + N_GRAPHS) * 4 + 256, stream);

    // CSR build (reused for all 3 layers)
    deg_kernel<<<EDGE_BLOCKS, 256, 0, stream>>>(e_dst, deg, N_EDGES);
    scan_phase1<<<SCAN_BLOCKS, 256, 0, stream>>>(deg, row_ptr, bsums, N_NODES);
    scan_phase2<<<1, 512, 0, stream>>>(bsums, boffs, SCAN_BLOCKS, row_ptr + N_NODES);
    scan_phase3<<<SCAN_BLOCKS, 256, 0, stream>>>(row_ptr, boffs, cursor, N_NODES);
    fill_kernel<<<EDGE_BLOCKS, 256, 0, stream>>>(e_src, e_dst, cursor, col_idx, N_EDGES);

    // layer 1 (project 128->64 BEFORE aggregation: linearity of W1)
    project_kernel<EMB><<<NODE_BLOCKS, 256, 0, stream>>>(x, c1_W1, y);
    gin_layer<<<NODE_BLOCKS, 256, 0, stream>>>(y, row_ptr, col_idx, c1_b1, c1_W2, c1_b2, h, 1);

    // layer 2
    project_kernel<HID><<<NODE_BLOCKS, 256, 0, stream>>>(h, c2_W1, y);
    gin_layer<<<NODE_BLOCKS, 256, 0, stream>>>(y, row_ptr, col_idx, c2_b1, c2_W2, c2_b2, h, 1);

    // layer 3 (no output relu)
    project_kernel<HID><<<NODE_BLOCKS, 256, 0, stream>>>(h, c3_W1, y);
    gin_layer<<<NODE_BLOCKS, 256, 0, stream>>>(y, row_ptr, col_idx, c3_b1, c3_W2, c3_b2, h, 0);

    // pool + head
    pool_kernel<<<64, 256, 0, stream>>>(h, batch, pool, counts, N_NODES);
    head_kernel<<<N_GRAPHS, 64, 0, stream>>>(pool, counts, fc1_W, fc1_b, predW, predb, out);
}

// Round 2
// 876.673 us; speedup vs baseline: 1.3103x; 1.3103x over previous
//
#include <hip/hip_runtime.h>
#include <math.h>

#define N_NODES 100000
#define N_EDGES 1600000
#define N_GRAPHS 64
#define EMB 128
#define HID 64

// ---------------- CSR build ----------------

__global__ void deg_kernel(const int* __restrict__ dst, int* __restrict__ deg, int e) {
    int i = blockIdx.x * 256 + threadIdx.x;
    if (i < e) atomicAdd(&deg[dst[i]], 1);
}

// phase 1: per-block (256 elems) exclusive scan; write block totals
__global__ void scan_phase1(const int* __restrict__ deg, int* __restrict__ excl,
                            int* __restrict__ blockSums, int n) {
    int i = blockIdx.x * 256 + threadIdx.x;
    int v = (i < n) ? deg[i] : 0;
    int lane = threadIdx.x & 63;
    int wid  = threadIdx.x >> 6;
    int incl = v;
    #pragma unroll
    for (int off = 1; off < 64; off <<= 1) {
        int t = __shfl_up(incl, off);
        if (lane >= off) incl += t;
    }
    __shared__ int wsum[4];
    if (lane == 63) wsum[wid] = incl;
    __syncthreads();
    int woff = 0;
    for (int w = 0; w < wid; ++w) woff += wsum[w];
    if (i < n) excl[i] = woff + incl - v;
    if (threadIdx.x == 255) blockSums[blockIdx.x] = woff + incl;
}

// phase 2: single block (512 threads) scans block sums (nb <= 512)
__global__ void scan_phase2(const int* __restrict__ blockSums, int* __restrict__ blockOffs,
                            int nb, int* __restrict__ total_out) {
    int i = threadIdx.x;
    int v = (i < nb) ? blockSums[i] : 0;
    int lane = i & 63, wid = i >> 6;
    int incl = v;
    #pragma unroll
    for (int off = 1; off < 64; off <<= 1) {
        int t = __shfl_up(incl, off);
        if (lane >= off) incl += t;
    }
    __shared__ int wsum[8];
    if (lane == 63) wsum[wid] = incl;
    __syncthreads();
    int woff = 0;
    for (int w = 0; w < wid; ++w) woff += wsum[w];
    if (i < nb) blockOffs[i] = woff + incl - v;
    if (i == 511) *total_out = woff + incl;
}

// phase 3: add block offsets in place; clone to cursor
__global__ void scan_phase3(int* __restrict__ row_ptr, const int* __restrict__ blockOffs,
                            int* __restrict__ cursor, int n) {
    int i = blockIdx.x * 256 + threadIdx.x;
    if (i < n) {
        int r = row_ptr[i] + blockOffs[blockIdx.x];
        row_ptr[i] = r;
        cursor[i]  = r;
    }
}

__global__ void fill_kernel(const int* __restrict__ src, const int* __restrict__ dst,
                            int* __restrict__ cursor, int* __restrict__ col_idx, int e) {
    int i = blockIdx.x * 256 + threadIdx.x;
    if (i < e) {
        int slot = atomicAdd(&cursor[dst[i]], 1);
        col_idx[slot] = src[i];
    }
}

// ---------------- dense projection: y = h @ W (Din -> 64), no bias ----------------
// v2: lane = node (64 nodes/wave), wave computes a 16-channel output slice.
// A rows read per-lane (float4, L1-served); W read on the SCALAR pipe
// (wave-uniform address via readfirstlane -> s_load), reused by all 64 lanes.

template <int DIN>
__global__ __launch_bounds__(256) void project_kernel(const float* __restrict__ h,
                                                      const float* __restrict__ W,
                                                      float* __restrict__ y) {
    int wid  = threadIdx.x >> 6;                 // 0..3 -> out-channel group
    int lane = threadIdx.x & 63;                 // node within tile
    int node = blockIdx.x * 64 + lane;
    bool valid = node < N_NODES;
    const float4* row = reinterpret_cast<const float4*>(h + (size_t)(valid ? node : 0) * DIN);
    int ob = __builtin_amdgcn_readfirstlane(wid * 16);   // force scalar uniformity

    float acc[16];
    #pragma unroll
    for (int o = 0; o < 16; ++o) acc[o] = 0.0f;

    #pragma unroll 4
    for (int k4 = 0; k4 < DIN / 4; ++k4) {
        float4 a = row[k4];
        #pragma unroll
        for (int kk = 0; kk < 4; ++kk) {
            int k = k4 * 4 + kk;
            float av = (kk == 0) ? a.x : (kk == 1) ? a.y : (kk == 2) ? a.z : a.w;
            const float* wr = W + k * 64 + ob;   // uniform address -> s_load
            #pragma unroll
            for (int o = 0; o < 16; ++o)
                acc[o] = fmaf(av, wr[o], acc[o]);
        }
    }

    if (valid) {
        float* yr = y + (size_t)node * 64 + ob;  // 16B-aligned (ob % 16 == 0)
        #pragma unroll
        for (int o4 = 0; o4 < 4; ++o4) {
            float4 v;
            v.x = acc[o4 * 4 + 0];
            v.y = acc[o4 * 4 + 1];
            v.z = acc[o4 * 4 + 2];
            v.w = acc[o4 * 4 + 3];
            *reinterpret_cast<float4*>(yr + o4 * 4) = v;
        }
    }
}

// ---------------- fused layer: gather-sum + bias + relu + GEMM2 + bias (+relu) ----------------

__global__ __launch_bounds__(256) void gin_layer(const float* __restrict__ y,
                                                 const int* __restrict__ row_ptr,
                                                 const int* __restrict__ col_idx,
                                                 const float* __restrict__ b1,
                                                 const float* __restrict__ W2,
                                                 const float* __restrict__ b2,
                                                 float* __restrict__ h, int relu_out) {
    __shared__ float sW2[64 * 64];
    __shared__ float st[4][64];
    for (int idx = threadIdx.x; idx < 64 * 64; idx += 256) sW2[idx] = W2[idx];

    int wid  = threadIdx.x >> 6;
    int lane = threadIdx.x & 63;
    int node = blockIdx.x * 4 + wid;

    int start = row_ptr[node];
    int end   = row_ptr[node + 1];
    float acc = y[(size_t)node * 64 + lane];

    for (int base = start; base < end; base += 64) {
        int cnt = end - base;
        if (cnt > 64) cnt = 64;
        int sidx = (base + lane < end) ? col_idx[base + lane] : 0;
        for (int k = 0; k < cnt; ++k) {
            int s = __shfl(sidx, k);
            acc += y[(size_t)s * 64 + lane];
        }
    }

    float t = fmaxf(acc + b1[lane], 0.0f);
    st[wid][lane] = t;
    __syncthreads();  // covers W2 staging + st

    float u = b2[lane];
    #pragma unroll 16
    for (int k = 0; k < 64; ++k)
        u = fmaf(st[wid][k], sW2[k * 64 + lane], u);
    if (relu_out) u = fmaxf(u, 0.0f);
    h[(size_t)node * 64 + lane] = u;
}

// ---------------- pooling: segment mean (batch is sorted) ----------------

__global__ void pool_kernel(const float* __restrict__ h, const int* __restrict__ batch,
                            float* __restrict__ pool, float* __restrict__ counts, int n) {
    int gwave = (blockIdx.x * blockDim.x + threadIdx.x) >> 6;
    int lane  = threadIdx.x & 63;
    int nwaves = (gridDim.x * blockDim.x) >> 6;
    int chunk = (n + nwaves - 1) / nwaves;
    int s = gwave * chunk;
    int e = min(n, s + chunk);
    if (s >= e) return;
    int cur = batch[s];
    float acc = 0.0f, cnt = 0.0f;
    for (int i = s; i < e; ++i) {
        int g = batch[i];
        if (g != cur) {
            atomicAdd(&pool[cur * 64 + lane], acc);
            if (lane == 0) atomicAdd(&counts[cur], cnt);
            cur = g; acc = 0.0f; cnt = 0.0f;
        }
        acc += h[(size_t)i * 64 + lane];
        cnt += 1.0f;
    }
    atomicAdd(&pool[cur * 64 + lane], acc);
    if (lane == 0) atomicAdd(&counts[cur], cnt);
}

// ---------------- head: pooled @ fc1 + b, @ pred + b, sigmoid ----------------

__global__ void head_kernel(const float* __restrict__ pool, const float* __restrict__ counts,
                            const float* __restrict__ fc1_W, const float* __restrict__ fc1_b,
                            const float* __restrict__ pred_W, const float* __restrict__ pred_b,
                            float* __restrict__ out) {
    int g = blockIdx.x;
    int t = threadIdx.x;  // 64 threads; lanes >= 32 idle for the dot
    float s = 0.0f;
    if (t < 32) {
        float cnt = fmaxf(counts[g], 1.0f);
        float inv = 1.0f / cnt;
        float f = fc1_b[t];
        #pragma unroll
        for (int k = 0; k < 64; ++k)
            f = fmaf(pool[g * 64 + k] * inv, fc1_W[k * 32 + t], f);
        s = f * pred_W[t];
    }
    #pragma unroll
    for (int off = 32; off > 0; off >>= 1) s += __shfl_down(s, off);
    if (t == 0) out[g] = 1.0f / (1.0f + expf(-(s + pred_b[0])));
}

// ---------------- launch ----------------

extern "C" void kernel_launch(void* const* d_in, const int* in_sizes, int n_in,
                              void* d_out, int out_size, void* d_ws, size_t ws_size,
                              hipStream_t stream) {
    const float* x      = (const float*)d_in[0];
    const int*   e_src  = (const int*)d_in[1];               // edge_index[0]
    const int*   e_dst  = ((const int*)d_in[1]) + N_EDGES;   // edge_index[1]
    const int*   batch  = (const int*)d_in[2];
    const float* c1_W1 = (const float*)d_in[3];
    const float* c1_b1 = (const float*)d_in[4];
    const float* c1_W2 = (const float*)d_in[5];
    const float* c1_b2 = (const float*)d_in[6];
    const float* c2_W1 = (const float*)d_in[7];
    const float* c2_b1 = (const float*)d_in[8];
    const float* c2_W2 = (const float*)d_in[9];
    const float* c2_b2 = (const float*)d_in[10];
    const float* c3_W1 = (const float*)d_in[11];
    const float* c3_b1 = (const float*)d_in[12];
    const float* c3_W2 = (const float*)d_in[13];
    const float* c3_b2 = (const float*)d_in[14];
    const float* fc1_W = (const float*)d_in[15];
    const float* fc1_b = (const float*)d_in[16];
    const float* predW = (const float*)d_in[17];
    const float* predb = (const float*)d_in[18];
    float* out = (float*)d_out;

    // workspace carve-up (aligned to 256B)
    char* ws = (char*)d_ws;
    size_t off = 0;
    auto carve = [&](size_t bytes) {
        char* p = ws + off;
        off += (bytes + 255) & ~(size_t)255;
        return p;
    };
    float* y        = (float*)carve((size_t)N_NODES * 64 * 4);
    float* h        = (float*)carve((size_t)N_NODES * 64 * 4);
    int*   deg      = (int*)carve((size_t)N_NODES * 4);
    int*   row_ptr  = (int*)carve(((size_t)N_NODES + 1) * 4);
    int*   cursor   = (int*)carve((size_t)N_NODES * 4);
    int*   col_idx  = (int*)carve((size_t)N_EDGES * 4);
    int*   bsums    = (int*)carve(512 * 4);
    int*   boffs    = (int*)carve(512 * 4);
    float* pool     = (float*)carve(N_GRAPHS * 64 * 4);
    float* counts   = (float*)carve(N_GRAPHS * 4);
    (void)ws_size; (void)n_in; (void)in_sizes; (void)out_size;

    const int SCAN_BLOCKS = (N_NODES + 255) / 256;     // 391
    const int EDGE_BLOCKS = (N_EDGES + 255) / 256;     // 6250
    const int NODE_BLOCKS = N_NODES / 4;               // 25000 (gin_layer: 4 nodes/block)
    const int PROJ_BLOCKS = (N_NODES + 63) / 64;       // 1563 (project: 64 nodes/block)

    // zero accumulators
    hipMemsetAsync(deg, 0, (size_t)N_NODES * 4, stream);
    hipMemsetAsync(pool, 0, (N_GRAPHS * 64 + N_GRAPHS) * 4 + 256, stream);

    // CSR build (reused for all 3 layers)
    deg_kernel<<<EDGE_BLOCKS, 256, 0, stream>>>(e_dst, deg, N_EDGES);
    scan_phase1<<<SCAN_BLOCKS, 256, 0, stream>>>(deg, row_ptr, bsums, N_NODES);
    scan_phase2<<<1, 512, 0, stream>>>(bsums, boffs, SCAN_BLOCKS, row_ptr + N_NODES);
    scan_phase3<<<SCAN_BLOCKS, 256, 0, stream>>>(row_ptr, boffs, cursor, N_NODES);
    fill_kernel<<<EDGE_BLOCKS, 256, 0, stream>>>(e_src, e_dst, cursor, col_idx, N_EDGES);

    // layer 1 (project 128->64 BEFORE aggregation: linearity of W1)
    project_kernel<EMB><<<PROJ_BLOCKS, 256, 0, stream>>>(x, c1_W1, y);
    gin_layer<<<NODE_BLOCKS, 256, 0, stream>>>(y, row_ptr, col_idx, c1_b1, c1_W2, c1_b2, h, 1);

    // layer 2
    project_kernel<HID><<<PROJ_BLOCKS, 256, 0, stream>>>(h, c2_W1, y);
    gin_layer<<<NODE_BLOCKS, 256, 0, stream>>>(y, row_ptr, col_idx, c2_b1, c2_W2, c2_b2, h, 1);

    // layer 3 (no output relu)
    project_kernel<HID><<<PROJ_BLOCKS, 256, 0, stream>>>(h, c3_W1, y);
    gin_layer<<<NODE_BLOCKS, 256, 0, stream>>>(y, row_ptr, col_idx, c3_b1, c3_W2, c3_b2, h, 0);

    // pool + head
    pool_kernel<<<64, 256, 0, stream>>>(h, batch, pool, counts, N_NODES);
    head_kernel<<<N_GRAPHS, 64, 0, stream>>>(pool, counts, fc1_W, fc1_b, predW, predb, out);
}

// Round 3
// 629.347 us; speedup vs baseline: 1.8253x; 1.3930x over previous
//
#include <hip/hip_runtime.h>
#include <math.h>

#define N_NODES 100000
#define N_EDGES 1600000
#define N_GRAPHS 64
#define EMB 128
#define HID 64

// ---------------- CSR build ----------------

__global__ void deg_kernel(const int* __restrict__ dst, int* __restrict__ deg, int e) {
    int i = blockIdx.x * 256 + threadIdx.x;
    if (i < e) atomicAdd(&deg[dst[i]], 1);
}

// phase 1: per-block (256 elems) exclusive scan; write block totals
__global__ void scan_phase1(const int* __restrict__ deg, int* __restrict__ excl,
                            int* __restrict__ blockSums, int n) {
    int i = blockIdx.x * 256 + threadIdx.x;
    int v = (i < n) ? deg[i] : 0;
    int lane = threadIdx.x & 63;
    int wid  = threadIdx.x >> 6;
    int incl = v;
    #pragma unroll
    for (int off = 1; off < 64; off <<= 1) {
        int t = __shfl_up(incl, off);
        if (lane >= off) incl += t;
    }
    __shared__ int wsum[4];
    if (lane == 63) wsum[wid] = incl;
    __syncthreads();
    int woff = 0;
    for (int w = 0; w < wid; ++w) woff += wsum[w];
    if (i < n) excl[i] = woff + incl - v;
    if (threadIdx.x == 255) blockSums[blockIdx.x] = woff + incl;
}

// phase 2: single block (512 threads) scans block sums (nb <= 512)
__global__ void scan_phase2(const int* __restrict__ blockSums, int* __restrict__ blockOffs,
                            int nb, int* __restrict__ total_out) {
    int i = threadIdx.x;
    int v = (i < nb) ? blockSums[i] : 0;
    int lane = i & 63, wid = i >> 6;
    int incl = v;
    #pragma unroll
    for (int off = 1; off < 64; off <<= 1) {
        int t = __shfl_up(incl, off);
        if (lane >= off) incl += t;
    }
    __shared__ int wsum[8];
    if (lane == 63) wsum[wid] = incl;
    __syncthreads();
    int woff = 0;
    for (int w = 0; w < wid; ++w) woff += wsum[w];
    if (i < nb) blockOffs[i] = woff + incl - v;
    if (i == 511) *total_out = woff + incl;
}

// phase 3: add block offsets in place; clone to cursor
__global__ void scan_phase3(int* __restrict__ row_ptr, const int* __restrict__ blockOffs,
                            int* __restrict__ cursor, int n) {
    int i = blockIdx.x * 256 + threadIdx.x;
    if (i < n) {
        int r = row_ptr[i] + blockOffs[blockIdx.x];
        row_ptr[i] = r;
        cursor[i]  = r;
    }
}

__global__ void fill_kernel(const int* __restrict__ src, const int* __restrict__ dst,
                            int* __restrict__ cursor, int* __restrict__ col_idx, int e) {
    int i = blockIdx.x * 256 + threadIdx.x;
    if (i < e) {
        int slot = atomicAdd(&cursor[dst[i]], 1);
        col_idx[slot] = src[i];
    }
}

// ---------------- dense projection: y = h @ W (Din -> 64), no bias ----------------
// lane = node (64 nodes/wave), wave computes a 16-channel output slice.
// W read at wave-uniform addresses (scalar pipe), reused by all 64 lanes.

template <int DIN>
__global__ __launch_bounds__(256) void project_kernel(const float* __restrict__ h,
                                                      const float* __restrict__ W,
                                                      float* __restrict__ y) {
    int wid  = threadIdx.x >> 6;                 // 0..3 -> out-channel group
    int lane = threadIdx.x & 63;                 // node within tile
    int node = blockIdx.x * 64 + lane;
    bool valid = node < N_NODES;
    const float4* row = reinterpret_cast<const float4*>(h + (size_t)(valid ? node : 0) * DIN);
    int ob = __builtin_amdgcn_readfirstlane(wid * 16);   // force scalar uniformity

    float acc[16];
    #pragma unroll
    for (int o = 0; o < 16; ++o) acc[o] = 0.0f;

    #pragma unroll 4
    for (int k4 = 0; k4 < DIN / 4; ++k4) {
        float4 a = row[k4];
        #pragma unroll
        for (int kk = 0; kk < 4; ++kk) {
            int k = k4 * 4 + kk;
            float av = (kk == 0) ? a.x : (kk == 1) ? a.y : (kk == 2) ? a.z : a.w;
            const float* wr = W + k * 64 + ob;   // uniform address -> s_load
            #pragma unroll
            for (int o = 0; o < 16; ++o)
                acc[o] = fmaf(av, wr[o], acc[o]);
        }
    }

    if (valid) {
        float* yr = y + (size_t)node * 64 + ob;  // 16B-aligned (ob % 16 == 0)
        #pragma unroll
        for (int o4 = 0; o4 < 4; ++o4) {
            float4 v;
            v.x = acc[o4 * 4 + 0];
            v.y = acc[o4 * 4 + 1];
            v.z = acc[o4 * 4 + 2];
            v.w = acc[o4 * 4 + 3];
            *reinterpret_cast<float4*>(yr + o4 * 4) = v;
        }
    }
}

// ---------------- fused layer: gather-sum + bias + relu + GEMM2 + bias (+relu) ----------------
// v3: lane = (e4 = lane>>4, c16 = lane&15). Each wave fetches 4 edge rows per
// load instruction (16 lanes x float4 = one 256B row per group); main loop
// keeps 16 rows in flight. Block = 16 nodes (4 per wave) to amortize W2 staging.

#define NPB 16  // nodes per block

__global__ __launch_bounds__(256) void gin_layer(const float* __restrict__ y,
                                                 const int* __restrict__ row_ptr,
                                                 const int* __restrict__ col_idx,
                                                 const float* __restrict__ b1,
                                                 const float* __restrict__ W2,
                                                 const float* __restrict__ b2,
                                                 float* __restrict__ h, int relu_out) {
    __shared__ float sW2[64 * 64];
    __shared__ float4 stv[4][16];

    // stage W2 (vectorized)
    {
        const float4* W4 = reinterpret_cast<const float4*>(W2);
        float4* s4 = reinterpret_cast<float4*>(sW2);
        #pragma unroll
        for (int i = 0; i < 4; ++i)
            s4[threadIdx.x + i * 256] = W4[threadIdx.x + i * 256];
    }
    __syncthreads();

    int wid  = threadIdx.x >> 6;
    int lane = threadIdx.x & 63;
    int e4   = lane >> 4;       // edge sub-group 0..3
    int c16  = lane & 15;       // float4 channel chunk 0..15

    const float4* y4 = reinterpret_cast<const float4*>(y);
    const float*  stf = reinterpret_cast<const float*>(&stv[wid][0]);
    float4 b1v = reinterpret_cast<const float4*>(b1)[c16];
    float  b2v = b2[lane];

    #pragma unroll 1
    for (int t = 0; t < 4; ++t) {
        int node = blockIdx.x * NPB + wid * 4 + t;

        int start = row_ptr[node];
        int end   = row_ptr[node + 1];

        float4 acc = make_float4(0.f, 0.f, 0.f, 0.f);
        if (e4 == 0) acc = y4[(size_t)node * 16 + c16];   // self term

        int base = start;
        // main: 16 edges per iteration, 4 row-loads in flight per lane-group
        for (; base + 16 <= end; base += 16) {
            int i0 = col_idx[base + e4];
            int i1 = col_idx[base + 4 + e4];
            int i2 = col_idx[base + 8 + e4];
            int i3 = col_idx[base + 12 + e4];
            float4 v0 = y4[(size_t)i0 * 16 + c16];
            float4 v1 = y4[(size_t)i1 * 16 + c16];
            float4 v2 = y4[(size_t)i2 * 16 + c16];
            float4 v3 = y4[(size_t)i3 * 16 + c16];
            acc.x += v0.x + v1.x + v2.x + v3.x;
            acc.y += v0.y + v1.y + v2.y + v3.y;
            acc.z += v0.z + v1.z + v2.z + v3.z;
            acc.w += v0.w + v1.w + v2.w + v3.w;
        }
        // tail: rem < 16, straight-line predicated (loads stay in flight)
        {
            float4 z = make_float4(0.f, 0.f, 0.f, 0.f);
            float4 v0 = z, v1 = z, v2 = z, v3 = z;
            if (base + e4 < end)      v0 = y4[(size_t)col_idx[base + e4] * 16 + c16];
            if (base + 4 + e4 < end)  v1 = y4[(size_t)col_idx[base + 4 + e4] * 16 + c16];
            if (base + 8 + e4 < end)  v2 = y4[(size_t)col_idx[base + 8 + e4] * 16 + c16];
            if (base + 12 + e4 < end) v3 = y4[(size_t)col_idx[base + 12 + e4] * 16 + c16];
            acc.x += v0.x + v1.x + v2.x + v3.x;
            acc.y += v0.y + v1.y + v2.y + v3.y;
            acc.z += v0.z + v1.z + v2.z + v3.z;
            acc.w += v0.w + v1.w + v2.w + v3.w;
        }

        // reduce across the 4 edge groups (lanes differing in bits 4,5)
        #pragma unroll
        for (int m = 16; m <= 32; m <<= 1) {
            acc.x += __shfl_xor(acc.x, m);
            acc.y += __shfl_xor(acc.y, m);
            acc.z += __shfl_xor(acc.z, m);
            acc.w += __shfl_xor(acc.w, m);
        }

        // bias + relu, publish to wave-private st (no barrier: same-wave LDS dep)
        if (e4 == 0) {
            float4 tv;
            tv.x = fmaxf(acc.x + b1v.x, 0.0f);
            tv.y = fmaxf(acc.y + b1v.y, 0.0f);
            tv.z = fmaxf(acc.z + b1v.z, 0.0f);
            tv.w = fmaxf(acc.w + b1v.w, 0.0f);
            stv[wid][c16] = tv;
        }

        // GEMM2: u[lane] = b2[lane] + sum_k st[k] * W2[k][lane]
        float u = b2v;
        #pragma unroll 16
        for (int k = 0; k < 64; ++k)
            u = fmaf(stf[k], sW2[k * 64 + lane], u);
        if (relu_out) u = fmaxf(u, 0.0f);
        h[(size_t)node * 64 + lane] = u;
    }
}

// ---------------- pooling: segment mean (batch is sorted) ----------------

__global__ void pool_kernel(const float* __restrict__ h, const int* __restrict__ batch,
                            float* __restrict__ pool, float* __restrict__ counts, int n) {
    int gwave = (blockIdx.x * blockDim.x + threadIdx.x) >> 6;
    int lane  = threadIdx.x & 63;
    int nwaves = (gridDim.x * blockDim.x) >> 6;
    int chunk = (n + nwaves - 1) / nwaves;
    int s = gwave * chunk;
    int e = min(n, s + chunk);
    if (s >= e) return;
    int cur = batch[s];
    float acc = 0.0f, cnt = 0.0f;
    for (int i = s; i < e; ++i) {
        int g = batch[i];
        if (g != cur) {
            atomicAdd(&pool[cur * 64 + lane], acc);
            if (lane == 0) atomicAdd(&counts[cur], cnt);
            cur = g; acc = 0.0f; cnt = 0.0f;
        }
        acc += h[(size_t)i * 64 + lane];
        cnt += 1.0f;
    }
    atomicAdd(&pool[cur * 64 + lane], acc);
    if (lane == 0) atomicAdd(&counts[cur], cnt);
}

// ---------------- head: pooled @ fc1 + b, @ pred + b, sigmoid ----------------

__global__ void head_kernel(const float* __restrict__ pool, const float* __restrict__ counts,
                            const float* __restrict__ fc1_W, const float* __restrict__ fc1_b,
                            const float* __restrict__ pred_W, const float* __restrict__ pred_b,
                            float* __restrict__ out) {
    int g = blockIdx.x;
    int t = threadIdx.x;  // 64 threads; lanes >= 32 idle for the dot
    float s = 0.0f;
    if (t < 32) {
        float cnt = fmaxf(counts[g], 1.0f);
        float inv = 1.0f / cnt;
        float f = fc1_b[t];
        #pragma unroll
        for (int k = 0; k < 64; ++k)
            f = fmaf(pool[g * 64 + k] * inv, fc1_W[k * 32 + t], f);
        s = f * pred_W[t];
    }
    #pragma unroll
    for (int off = 32; off > 0; off >>= 1) s += __shfl_down(s, off);
    if (t == 0) out[g] = 1.0f / (1.0f + expf(-(s + pred_b[0])));
}

// ---------------- launch ----------------

extern "C" void kernel_launch(void* const* d_in, const int* in_sizes, int n_in,
                              void* d_out, int out_size, void* d_ws, size_t ws_size,
                              hipStream_t stream) {
    const float* x      = (const float*)d_in[0];
    const int*   e_src  = (const int*)d_in[1];               // edge_index[0]
    const int*   e_dst  = ((const int*)d_in[1]) + N_EDGES;   // edge_index[1]
    const int*   batch  = (const int*)d_in[2];
    const float* c1_W1 = (const float*)d_in[3];
    const float* c1_b1 = (const float*)d_in[4];
    const float* c1_W2 = (const float*)d_in[5];
    const float* c1_b2 = (const float*)d_in[6];
    const float* c2_W1 = (const float*)d_in[7];
    const float* c2_b1 = (const float*)d_in[8];
    const float* c2_W2 = (const float*)d_in[9];
    const float* c2_b2 = (const float*)d_in[10];
    const float* c3_W1 = (const float*)d_in[11];
    const float* c3_b1 = (const float*)d_in[12];
    const float* c3_W2 = (const float*)d_in[13];
    const float* c3_b2 = (const float*)d_in[14];
    const float* fc1_W = (const float*)d_in[15];
    const float* fc1_b = (const float*)d_in[16];
    const float* predW = (const float*)d_in[17];
    const float* predb = (const float*)d_in[18];
    float* out = (float*)d_out;

    // workspace carve-up (aligned to 256B)
    char* ws = (char*)d_ws;
    size_t off = 0;
    auto carve = [&](size_t bytes) {
        char* p = ws + off;
        off += (bytes + 255) & ~(size_t)255;
        return p;
    };
    float* y        = (float*)carve((size_t)N_NODES * 64 * 4);
    float* h        = (float*)carve((size_t)N_NODES * 64 * 4);
    int*   deg      = (int*)carve((size_t)N_NODES * 4);
    int*   row_ptr  = (int*)carve(((size_t)N_NODES + 1) * 4);
    int*   cursor   = (int*)carve((size_t)N_NODES * 4);
    int*   col_idx  = (int*)carve((size_t)N_EDGES * 4);
    int*   bsums    = (int*)carve(512 * 4);
    int*   boffs    = (int*)carve(512 * 4);
    float* pool     = (float*)carve(N_GRAPHS * 64 * 4);
    float* counts   = (float*)carve(N_GRAPHS * 4);
    (void)ws_size; (void)n_in; (void)in_sizes; (void)out_size;

    const int SCAN_BLOCKS = (N_NODES + 255) / 256;     // 391
    const int EDGE_BLOCKS = (N_EDGES + 255) / 256;     // 6250
    const int GIN_BLOCKS  = (N_NODES + NPB - 1) / NPB; // 6250 (16 nodes/block)
    const int PROJ_BLOCKS = (N_NODES + 63) / 64;       // 1563 (64 nodes/block)

    // zero accumulators
    hipMemsetAsync(deg, 0, (size_t)N_NODES * 4, stream);
    hipMemsetAsync(pool, 0, (N_GRAPHS * 64 + N_GRAPHS) * 4 + 256, stream);

    // CSR build (reused for all 3 layers)
    deg_kernel<<<EDGE_BLOCKS, 256, 0, stream>>>(e_dst, deg, N_EDGES);
    scan_phase1<<<SCAN_BLOCKS, 256, 0, stream>>>(deg, row_ptr, bsums, N_NODES);
    scan_phase2<<<1, 512, 0, stream>>>(bsums, boffs, SCAN_BLOCKS, row_ptr + N_NODES);
    scan_phase3<<<SCAN_BLOCKS, 256, 0, stream>>>(row_ptr, boffs, cursor, N_NODES);
    fill_kernel<<<EDGE_BLOCKS, 256, 0, stream>>>(e_src, e_dst, cursor, col_idx, N_EDGES);

    // layer 1 (project 128->64 BEFORE aggregation: linearity of W1)
    project_kernel<EMB><<<PROJ_BLOCKS, 256, 0, stream>>>(x, c1_W1, y);
    gin_layer<<<GIN_BLOCKS, 256, 0, stream>>>(y, row_ptr, col_idx, c1_b1, c1_W2, c1_b2, h, 1);

    // layer 2
    project_kernel<HID><<<PROJ_BLOCKS, 256, 0, stream>>>(h, c2_W1, y);
    gin_layer<<<GIN_BLOCKS, 256, 0, stream>>>(y, row_ptr, col_idx, c2_b1, c2_W2, c2_b2, h, 1);

    // layer 3 (no output relu)
    project_kernel<HID><<<PROJ_BLOCKS, 256, 0, stream>>>(h, c3_W1, y);
    gin_layer<<<GIN_BLOCKS, 256, 0, stream>>>(y, row_ptr, col_idx, c3_b1, c3_W2, c3_b2, h, 0);

    // pool + head
    pool_kernel<<<64, 256, 0, stream>>>(h, batch, pool, counts, N_NODES);
    head_kernel<<<N_GRAPHS, 64, 0, stream>>>(pool, counts, fc1_W, fc1_b, predW, predb, out);
}

// Round 4
// 501.243 us; speedup vs baseline: 2.2918x; 1.2556x over previous
//
#include <hip/hip_runtime.h>
#include <math.h>

#define N_NODES 100000
#define N_EDGES 1600000
#define N_GRAPHS 64
#define EMB 128
#define HID 64

// ---------------- CSR build ----------------

__global__ void deg_kernel(const int* __restrict__ dst, int* __restrict__ deg, int e) {
    int i = blockIdx.x * 256 + threadIdx.x;
    if (i < e) atomicAdd(&deg[dst[i]], 1);
}

// phase 1: per-block (256 elems) exclusive scan; write block totals
__global__ void scan_phase1(const int* __restrict__ deg, int* __restrict__ excl,
                            int* __restrict__ blockSums, int n) {
    int i = blockIdx.x * 256 + threadIdx.x;
    int v = (i < n) ? deg[i] : 0;
    int lane = threadIdx.x & 63;
    int wid  = threadIdx.x >> 6;
    int incl = v;
    #pragma unroll
    for (int off = 1; off < 64; off <<= 1) {
        int t = __shfl_up(incl, off);
        if (lane >= off) incl += t;
    }
    __shared__ int wsum[4];
    if (lane == 63) wsum[wid] = incl;
    __syncthreads();
    int woff = 0;
    for (int w = 0; w < wid; ++w) woff += wsum[w];
    if (i < n) excl[i] = woff + incl - v;
    if (threadIdx.x == 255) blockSums[blockIdx.x] = woff + incl;
}

// phase 2: single block (512 threads) scans block sums (nb <= 512)
__global__ void scan_phase2(const int* __restrict__ blockSums, int* __restrict__ blockOffs,
                            int nb, int* __restrict__ total_out) {
    int i = threadIdx.x;
    int v = (i < nb) ? blockSums[i] : 0;
    int lane = i & 63, wid = i >> 6;
    int incl = v;
    #pragma unroll
    for (int off = 1; off < 64; off <<= 1) {
        int t = __shfl_up(incl, off);
        if (lane >= off) incl += t;
    }
    __shared__ int wsum[8];
    if (lane == 63) wsum[wid] = incl;
    __syncthreads();
    int woff = 0;
    for (int w = 0; w < wid; ++w) woff += wsum[w];
    if (i < nb) blockOffs[i] = woff + incl - v;
    if (i == 511) *total_out = woff + incl;
}

// phase 3: add block offsets in place; clone to cursor
__global__ void scan_phase3(int* __restrict__ row_ptr, const int* __restrict__ blockOffs,
                            int* __restrict__ cursor, int n) {
    int i = blockIdx.x * 256 + threadIdx.x;
    if (i < n) {
        int r = row_ptr[i] + blockOffs[blockIdx.x];
        row_ptr[i] = r;
        cursor[i]  = r;
    }
}

__global__ void fill_kernel(const int* __restrict__ src, const int* __restrict__ dst,
                            int* __restrict__ cursor, int* __restrict__ col_idx, int e) {
    int i = blockIdx.x * 256 + threadIdx.x;
    if (i < e) {
        int slot = atomicAdd(&cursor[dst[i]], 1);
        col_idx[slot] = src[i];
    }
}

// ---------------- dense projection: y = h @ W (Din -> 64), no bias ----------------
// lane = node (64 nodes/wave), wave computes a 16-channel output slice.
// W read at wave-uniform addresses (scalar pipe), reused by all 64 lanes.

template <int DIN>
__global__ __launch_bounds__(256) void project_kernel(const float* __restrict__ h,
                                                      const float* __restrict__ W,
                                                      float* __restrict__ y) {
    int wid  = threadIdx.x >> 6;                 // 0..3 -> out-channel group
    int lane = threadIdx.x & 63;                 // node within tile
    int node = blockIdx.x * 64 + lane;
    bool valid = node < N_NODES;
    const float4* row = reinterpret_cast<const float4*>(h + (size_t)(valid ? node : 0) * DIN);
    int ob = __builtin_amdgcn_readfirstlane(wid * 16);   // force scalar uniformity

    float acc[16];
    #pragma unroll
    for (int o = 0; o < 16; ++o) acc[o] = 0.0f;

    #pragma unroll 4
    for (int k4 = 0; k4 < DIN / 4; ++k4) {
        float4 a = row[k4];
        #pragma unroll
        for (int kk = 0; kk < 4; ++kk) {
            int k = k4 * 4 + kk;
            float av = (kk == 0) ? a.x : (kk == 1) ? a.y : (kk == 2) ? a.z : a.w;
            const float* wr = W + k * 64 + ob;   // uniform address -> s_load
            #pragma unroll
            for (int o = 0; o < 16; ++o)
                acc[o] = fmaf(av, wr[o], acc[o]);
        }
    }

    if (valid) {
        float* yr = y + (size_t)node * 64 + ob;  // 16B-aligned (ob % 16 == 0)
        #pragma unroll
        for (int o4 = 0; o4 < 4; ++o4) {
            float4 v;
            v.x = acc[o4 * 4 + 0];
            v.y = acc[o4 * 4 + 1];
            v.z = acc[o4 * 4 + 2];
            v.w = acc[o4 * 4 + 3];
            *reinterpret_cast<float4*>(yr + o4 * 4) = v;
        }
    }
}

// ---------------- fused layer: gather-sum + bias + relu + GEMM2 + bias (+relu) ----------------
// lane = (e4 = lane>>4, c16 = lane&15). Each wave fetches 4 edge rows per
// load instruction (16 lanes x float4 = one 256B row per group); main loop
// keeps 16 rows in flight. Block = 16 nodes (4 per wave) to amortize W2 staging.

#define NPB 16  // nodes per block

__global__ __launch_bounds__(256) void gin_layer(const float* __restrict__ y,
                                                 const int* __restrict__ row_ptr,
                                                 const int* __restrict__ col_idx,
                                                 const float* __restrict__ b1,
                                                 const float* __restrict__ W2,
                                                 const float* __restrict__ b2,
                                                 float* __restrict__ h, int relu_out) {
    __shared__ float sW2[64 * 64];
    __shared__ float4 stv[4][16];

    // stage W2 (vectorized)
    {
        const float4* W4 = reinterpret_cast<const float4*>(W2);
        float4* s4 = reinterpret_cast<float4*>(sW2);
        #pragma unroll
        for (int i = 0; i < 4; ++i)
            s4[threadIdx.x + i * 256] = W4[threadIdx.x + i * 256];
    }
    __syncthreads();

    int wid  = threadIdx.x >> 6;
    int lane = threadIdx.x & 63;
    int e4   = lane >> 4;       // edge sub-group 0..3
    int c16  = lane & 15;       // float4 channel chunk 0..15

    const float4* y4 = reinterpret_cast<const float4*>(y);
    const float*  stf = reinterpret_cast<const float*>(&stv[wid][0]);
    float4 b1v = reinterpret_cast<const float4*>(b1)[c16];
    float  b2v = b2[lane];

    #pragma unroll 1
    for (int t = 0; t < 4; ++t) {
        int node = blockIdx.x * NPB + wid * 4 + t;

        int start = row_ptr[node];
        int end   = row_ptr[node + 1];

        float4 acc = make_float4(0.f, 0.f, 0.f, 0.f);
        if (e4 == 0) acc = y4[(size_t)node * 16 + c16];   // self term

        int base = start;
        // main: 16 edges per iteration, 4 row-loads in flight per lane-group
        for (; base + 16 <= end; base += 16) {
            int i0 = col_idx[base + e4];
            int i1 = col_idx[base + 4 + e4];
            int i2 = col_idx[base + 8 + e4];
            int i3 = col_idx[base + 12 + e4];
            float4 v0 = y4[(size_t)i0 * 16 + c16];
            float4 v1 = y4[(size_t)i1 * 16 + c16];
            float4 v2 = y4[(size_t)i2 * 16 + c16];
            float4 v3 = y4[(size_t)i3 * 16 + c16];
            acc.x += v0.x + v1.x + v2.x + v3.x;
            acc.y += v0.y + v1.y + v2.y + v3.y;
            acc.z += v0.z + v1.z + v2.z + v3.z;
            acc.w += v0.w + v1.w + v2.w + v3.w;
        }
        // tail: rem < 16, straight-line predicated (loads stay in flight)
        {
            float4 z = make_float4(0.f, 0.f, 0.f, 0.f);
            float4 v0 = z, v1 = z, v2 = z, v3 = z;
            if (base + e4 < end)      v0 = y4[(size_t)col_idx[base + e4] * 16 + c16];
            if (base + 4 + e4 < end)  v1 = y4[(size_t)col_idx[base + 4 + e4] * 16 + c16];
            if (base + 8 + e4 < end)  v2 = y4[(size_t)col_idx[base + 8 + e4] * 16 + c16];
            if (base + 12 + e4 < end) v3 = y4[(size_t)col_idx[base + 12 + e4] * 16 + c16];
            acc.x += v0.x + v1.x + v2.x + v3.x;
            acc.y += v0.y + v1.y + v2.y + v3.y;
            acc.z += v0.z + v1.z + v2.z + v3.z;
            acc.w += v0.w + v1.w + v2.w + v3.w;
        }

        // reduce across the 4 edge groups (lanes differing in bits 4,5)
        #pragma unroll
        for (int m = 16; m <= 32; m <<= 1) {
            acc.x += __shfl_xor(acc.x, m);
            acc.y += __shfl_xor(acc.y, m);
            acc.z += __shfl_xor(acc.z, m);
            acc.w += __shfl_xor(acc.w, m);
        }

        // bias + relu, publish to wave-private st (no barrier: same-wave LDS dep)
        if (e4 == 0) {
            float4 tv;
            tv.x = fmaxf(acc.x + b1v.x, 0.0f);
            tv.y = fmaxf(acc.y + b1v.y, 0.0f);
            tv.z = fmaxf(acc.z + b1v.z, 0.0f);
            tv.w = fmaxf(acc.w + b1v.w, 0.0f);
            stv[wid][c16] = tv;
        }

        // GEMM2: u[lane] = b2[lane] + sum_k st[k] * W2[k][lane]
        float u = b2v;
        #pragma unroll 16
        for (int k = 0; k < 64; ++k)
            u = fmaf(stf[k], sW2[k * 64 + lane], u);
        if (relu_out) u = fmaxf(u, 0.0f);
        h[(size_t)node * 64 + lane] = u;
    }
}

// ---------------- pooling: segment mean (batch is sorted) ----------------
// v2: wave per 64-node chunk (1563 waves). Batch ids loaded once per lane and
// shfl-broadcast; rows loaded 8-at-a-time (8 loads in flight). Flushes are
// wave-uniform and rare (~1.05 per chunk).

__global__ __launch_bounds__(256) void pool_kernel(const float* __restrict__ h,
                                                   const int* __restrict__ batch,
                                                   float* __restrict__ pool,
                                                   float* __restrict__ counts, int n) {
    int gwave = (blockIdx.x * 256 + threadIdx.x) >> 6;
    int lane  = threadIdx.x & 63;
    int s = gwave * 64;
    if (s >= n) return;
    int nhere = min(64, n - s);

    int bv = (s + lane < n) ? batch[s + lane] : -1;
    int cur = __shfl(bv, 0);
    float acc = 0.0f, cnt = 0.0f;

    #pragma unroll 1
    for (int i0 = 0; i0 < 64; i0 += 8) {
        float v[8];
        #pragma unroll
        for (int j = 0; j < 8; ++j) {
            int i = i0 + j;
            v[j] = (i < nhere) ? h[(size_t)(s + i) * 64 + lane] : 0.0f;
        }
        #pragma unroll
        for (int j = 0; j < 8; ++j) {
            int i = i0 + j;
            if (i < nhere) {
                int g = __shfl(bv, i);
                if (g != cur) {   // wave-uniform, rare
                    atomicAdd(&pool[cur * 64 + lane], acc);
                    if (lane == 0) atomicAdd(&counts[cur], cnt);
                    cur = g; acc = 0.0f; cnt = 0.0f;
                }
                acc += v[j];
                cnt += 1.0f;
            }
        }
    }
    atomicAdd(&pool[cur * 64 + lane], acc);
    if (lane == 0) atomicAdd(&counts[cur], cnt);
}

// ---------------- head: pooled @ fc1 + b, @ pred + b, sigmoid ----------------

__global__ void head_kernel(const float* __restrict__ pool, const float* __restrict__ counts,
                            const float* __restrict__ fc1_W, const float* __restrict__ fc1_b,
                            const float* __restrict__ pred_W, const float* __restrict__ pred_b,
                            float* __restrict__ out) {
    int g = blockIdx.x;
    int t = threadIdx.x;  // 64 threads; lanes >= 32 idle for the dot
    float s = 0.0f;
    if (t < 32) {
        float cnt = fmaxf(counts[g], 1.0f);
        float inv = 1.0f / cnt;
        float f = fc1_b[t];
        #pragma unroll
        for (int k = 0; k < 64; ++k)
            f = fmaf(pool[g * 64 + k] * inv, fc1_W[k * 32 + t], f);
        s = f * pred_W[t];
    }
    #pragma unroll
    for (int off = 32; off > 0; off >>= 1) s += __shfl_down(s, off);
    if (t == 0) out[g] = 1.0f / (1.0f + expf(-(s + pred_b[0])));
}

// ---------------- launch ----------------

extern "C" void kernel_launch(void* const* d_in, const int* in_sizes, int n_in,
                              void* d_out, int out_size, void* d_ws, size_t ws_size,
                              hipStream_t stream) {
    const float* x      = (const float*)d_in[0];
    const int*   e_src  = (const int*)d_in[1];               // edge_index[0]
    const int*   e_dst  = ((const int*)d_in[1]) + N_EDGES;   // edge_index[1]
    const int*   batch  = (const int*)d_in[2];
    const float* c1_W1 = (const float*)d_in[3];
    const float* c1_b1 = (const float*)d_in[4];
    const float* c1_W2 = (const float*)d_in[5];
    const float* c1_b2 = (const float*)d_in[6];
    const float* c2_W1 = (const float*)d_in[7];
    const float* c2_b1 = (const float*)d_in[8];
    const float* c2_W2 = (const float*)d_in[9];
    const float* c2_b2 = (const float*)d_in[10];
    const float* c3_W1 = (const float*)d_in[11];
    const float* c3_b1 = (const float*)d_in[12];
    const float* c3_W2 = (const float*)d_in[13];
    const float* c3_b2 = (const float*)d_in[14];
    const float* fc1_W = (const float*)d_in[15];
    const float* fc1_b = (const float*)d_in[16];
    const float* predW = (const float*)d_in[17];
    const float* predb = (const float*)d_in[18];
    float* out = (float*)d_out;

    // workspace carve-up (aligned to 256B)
    char* ws = (char*)d_ws;
    size_t off = 0;
    auto carve = [&](size_t bytes) {
        char* p = ws + off;
        off += (bytes + 255) & ~(size_t)255;
        return p;
    };
    float* y        = (float*)carve((size_t)N_NODES * 64 * 4);
    float* h        = (float*)carve((size_t)N_NODES * 64 * 4);
    int*   deg      = (int*)carve((size_t)N_NODES * 4);
    int*   row_ptr  = (int*)carve(((size_t)N_NODES + 1) * 4);
    int*   cursor   = (int*)carve((size_t)N_NODES * 4);
    int*   col_idx  = (int*)carve((size_t)N_EDGES * 4);
    int*   bsums    = (int*)carve(512 * 4);
    int*   boffs    = (int*)carve(512 * 4);
    float* pool     = (float*)carve(N_GRAPHS * 64 * 4);
    float* counts   = (float*)carve(N_GRAPHS * 4);
    (void)ws_size; (void)n_in; (void)in_sizes; (void)out_size;

    const int SCAN_BLOCKS = (N_NODES + 255) / 256;     // 391
    const int EDGE_BLOCKS = (N_EDGES + 255) / 256;     // 6250
    const int GIN_BLOCKS  = (N_NODES + NPB - 1) / NPB; // 6250 (16 nodes/block)
    const int PROJ_BLOCKS = (N_NODES + 63) / 64;       // 1563 (64 nodes/block)
    const int POOL_BLOCKS = (N_NODES + 255) / 256;     // 391 (4 waves x 64 nodes)

    // zero accumulators
    hipMemsetAsync(deg, 0, (size_t)N_NODES * 4, stream);
    hipMemsetAsync(pool, 0, (N_GRAPHS * 64 + N_GRAPHS) * 4 + 256, stream);

    // CSR build (reused for all 3 layers)
    deg_kernel<<<EDGE_BLOCKS, 256, 0, stream>>>(e_dst, deg, N_EDGES);
    scan_phase1<<<SCAN_BLOCKS, 256, 0, stream>>>(deg, row_ptr, bsums, N_NODES);
    scan_phase2<<<1, 512, 0, stream>>>(bsums, boffs, SCAN_BLOCKS, row_ptr + N_NODES);
    scan_phase3<<<SCAN_BLOCKS, 256, 0, stream>>>(row_ptr, boffs, cursor, N_NODES);
    fill_kernel<<<EDGE_BLOCKS, 256, 0, stream>>>(e_src, e_dst, cursor, col_idx, N_EDGES);

    // layer 1 (project 128->64 BEFORE aggregation: linearity of W1)
    project_kernel<EMB><<<PROJ_BLOCKS, 256, 0, stream>>>(x, c1_W1, y);
    gin_layer<<<GIN_BLOCKS, 256, 0, stream>>>(y, row_ptr, col_idx, c1_b1, c1_W2, c1_b2, h, 1);

    // layer 2
    project_kernel<HID><<<PROJ_BLOCKS, 256, 0, stream>>>(h, c2_W1, y);
    gin_layer<<<GIN_BLOCKS, 256, 0, stream>>>(y, row_ptr, col_idx, c2_b1, c2_W2, c2_b2, h, 1);

    // layer 3 (no output relu)
    project_kernel<HID><<<PROJ_BLOCKS, 256, 0, stream>>>(h, c3_W1, y);
    gin_layer<<<GIN_BLOCKS, 256, 0, stream>>>(y, row_ptr, col_idx, c3_b1, c3_W2, c3_b2, h, 0);

    // pool + head
    pool_kernel<<<POOL_BLOCKS, 256, 0, stream>>>(h, batch, pool, counts, N_NODES);
    head_kernel<<<N_GRAPHS, 64, 0, stream>>>(pool, counts, fc1_W, fc1_b, predW, predb, out);
}

// Round 5
// 363.234 us; speedup vs baseline: 3.1625x; 1.3799x over previous
//
#include <hip/hip_runtime.h>
#include <math.h>

#define N_NODES 100000
#define N_EDGES 1600000
#define N_GRAPHS 64
#define EMB 128
#define HID 64

#define BUCKET_BITS 9
#define BUCKET_SZ   512
#define NB          196   // ceil(N_NODES / 512)
#define EPB         4096  // edges per block in bucket passes
#define P12_BLOCKS  391   // ceil(N_EDGES / 4096)

// ---------------- block-wide exclusive scan over 256 threads ----------------

__device__ inline int block_scan_excl_256(int v) {
    int t = threadIdx.x;
    int lane = t & 63, wid = t >> 6;
    int incl = v;
    #pragma unroll
    for (int off = 1; off < 64; off <<= 1) {
        int u = __shfl_up(incl, off);
        if (lane >= off) incl += u;
    }
    __shared__ int wsum[4];
    if (lane == 63) wsum[wid] = incl;
    __syncthreads();
    int woff = 0;
    for (int w = 0; w < wid; ++w) woff += wsum[w];
    __syncthreads();
    return woff + incl - v;
}

// ---------------- CSR build via bucket semi-sort ----------------
// pass 1: count edges per 512-node dst bucket (LDS histogram -> few global atomics)

__global__ __launch_bounds__(256) void bucket_count(const int* __restrict__ dst,
                                                    int* __restrict__ bucketCnt, int e) {
    __shared__ int bins[NB];
    for (int i = threadIdx.x; i < NB; i += 256) bins[i] = 0;
    __syncthreads();
    int base = blockIdx.x * EPB;
    #pragma unroll
    for (int j = 0; j < 16; ++j) {
        int i = base + j * 256 + threadIdx.x;
        if (i < e) atomicAdd(&bins[dst[i] >> BUCKET_BITS], 1);
    }
    __syncthreads();
    for (int i = threadIdx.x; i < NB; i += 256)
        if (bins[i]) atomicAdd(&bucketCnt[i], bins[i]);
}

// scan bucket counts (1 block); init cursor; finalize row_ptr[N]

__global__ void bucket_scan(const int* __restrict__ bucketCnt, int* __restrict__ bucketOff,
                            int* __restrict__ bucketCur, int* __restrict__ row_ptr) {
    int t = threadIdx.x;
    int v = (t < NB) ? bucketCnt[t] : 0;
    int excl = block_scan_excl_256(v);
    if (t < NB) { bucketOff[t] = excl; bucketCur[t] = excl; }
    if (t == 0) { bucketOff[NB] = N_EDGES; row_ptr[N_NODES] = N_EDGES; }
}

// pass 2: scatter edges into bucket-sorted order (uint2 = {dst, src}).
// LDS-stage the block's 4096 edges grouped by bucket, then write contiguous runs.

__global__ __launch_bounds__(256) void bucket_scatter(const int* __restrict__ src,
                                                      const int* __restrict__ dst,
                                                      int* __restrict__ bucketCur,
                                                      uint2* __restrict__ sorted, int e) {
    __shared__ int bins[NB];
    __shared__ int lbase[NB];
    __shared__ int gbase[NB];
    __shared__ int cur[NB];
    __shared__ uint2 stage[EPB];   // 32 KB

    for (int i = threadIdx.x; i < NB; i += 256) bins[i] = 0;
    __syncthreads();

    int base = blockIdx.x * EPB;
    #pragma unroll
    for (int j = 0; j < 16; ++j) {
        int i = base + j * 256 + threadIdx.x;
        if (i < e) atomicAdd(&bins[dst[i] >> BUCKET_BITS], 1);
    }
    __syncthreads();

    int t = threadIdx.x;
    int v = (t < NB) ? bins[t] : 0;
    int excl = block_scan_excl_256(v);
    if (t < NB) {
        lbase[t] = excl;
        cur[t]   = excl;
        gbase[t] = v ? atomicAdd(&bucketCur[t], v) : 0;
    }
    __syncthreads();

    #pragma unroll
    for (int j = 0; j < 16; ++j) {
        int i = base + j * 256 + threadIdx.x;
        if (i < e) {
            int d = dst[i], s = src[i];
            int p = atomicAdd(&cur[d >> BUCKET_BITS], 1);
            stage[p] = make_uint2((unsigned)d, (unsigned)s);
        }
    }
    __syncthreads();

    int cnt = min(EPB, e - base);
    for (int idx = threadIdx.x; idx < cnt; idx += 256) {
        uint2 ed = stage[idx];
        int b = (int)(ed.x >> BUCKET_BITS);
        sorted[gbase[b] + (idx - lbase[b])] = ed;   // contiguous runs per bucket
    }
}

// pass 3: one block per bucket -> local histogram, scan, row_ptr, col_idx fill.
// All scatter writes land in the block's private ~32KB col_idx region.

__global__ __launch_bounds__(256) void bucket_csr(const uint2* __restrict__ sorted,
                                                  const int* __restrict__ bucketOff,
                                                  int* __restrict__ row_ptr,
                                                  int* __restrict__ col_idx) {
    int b  = blockIdx.x;
    int S  = bucketOff[b];
    int Eb = bucketOff[b + 1];
    int n0 = b << BUCKET_BITS;
    int nNodes = min(BUCKET_SZ, N_NODES - n0);

    __shared__ int cnt[BUCKET_SZ];
    __shared__ int excl[BUCKET_SZ];
    __shared__ int cur[BUCKET_SZ];

    for (int i = threadIdx.x; i < BUCKET_SZ; i += 256) cnt[i] = 0;
    __syncthreads();

    for (int idx = S + threadIdx.x; idx < Eb; idx += 256)
        atomicAdd(&cnt[(int)sorted[idx].x - n0], 1);
    __syncthreads();

    int t = threadIdx.x;
    int v = cnt[2 * t] + cnt[2 * t + 1];
    int pe = block_scan_excl_256(v);
    excl[2 * t]     = pe;
    excl[2 * t + 1] = pe + cnt[2 * t];
    __syncthreads();

    for (int i = threadIdx.x; i < nNodes; i += 256)
        row_ptr[n0 + i] = S + excl[i];
    for (int i = threadIdx.x; i < BUCKET_SZ; i += 256) cur[i] = excl[i];
    __syncthreads();

    for (int idx = S + threadIdx.x; idx < Eb; idx += 256) {
        uint2 ed = sorted[idx];
        int ln = (int)ed.x - n0;
        int slot = S + atomicAdd(&cur[ln], 1);
        col_idx[slot] = (int)ed.y;
    }
}

// ---------------- dense projection: y = h @ W (Din -> 64), no bias ----------------
// lane = node (64 nodes/wave), wave computes a 16-channel output slice.
// W read at wave-uniform addresses (scalar pipe), reused by all 64 lanes.

template <int DIN>
__global__ __launch_bounds__(256) void project_kernel(const float* __restrict__ h,
                                                      const float* __restrict__ W,
                                                      float* __restrict__ y) {
    int wid  = threadIdx.x >> 6;                 // 0..3 -> out-channel group
    int lane = threadIdx.x & 63;                 // node within tile
    int node = blockIdx.x * 64 + lane;
    bool valid = node < N_NODES;
    const float4* row = reinterpret_cast<const float4*>(h + (size_t)(valid ? node : 0) * DIN);
    int ob = __builtin_amdgcn_readfirstlane(wid * 16);   // force scalar uniformity

    float acc[16];
    #pragma unroll
    for (int o = 0; o < 16; ++o) acc[o] = 0.0f;

    #pragma unroll 4
    for (int k4 = 0; k4 < DIN / 4; ++k4) {
        float4 a = row[k4];
        #pragma unroll
        for (int kk = 0; kk < 4; ++kk) {
            int k = k4 * 4 + kk;
            float av = (kk == 0) ? a.x : (kk == 1) ? a.y : (kk == 2) ? a.z : a.w;
            const float* wr = W + k * 64 + ob;   // uniform address -> s_load
            #pragma unroll
            for (int o = 0; o < 16; ++o)
                acc[o] = fmaf(av, wr[o], acc[o]);
        }
    }

    if (valid) {
        float* yr = y + (size_t)node * 64 + ob;  // 16B-aligned (ob % 16 == 0)
        #pragma unroll
        for (int o4 = 0; o4 < 4; ++o4) {
            float4 v;
            v.x = acc[o4 * 4 + 0];
            v.y = acc[o4 * 4 + 1];
            v.z = acc[o4 * 4 + 2];
            v.w = acc[o4 * 4 + 3];
            *reinterpret_cast<float4*>(yr + o4 * 4) = v;
        }
    }
}

// ---------------- fused layer: gather-sum + bias + relu + GEMM2 + bias (+relu) ----------------
// lane = (e4 = lane>>4, c16 = lane&15). Each wave fetches 4 edge rows per
// load instruction (16 lanes x float4 = one 256B row per group); main loop
// keeps 16 rows in flight. Block = 16 nodes (4 per wave) to amortize W2 staging.

#define NPB 16  // nodes per block

__global__ __launch_bounds__(256) void gin_layer(const float* __restrict__ y,
                                                 const int* __restrict__ row_ptr,
                                                 const int* __restrict__ col_idx,
                                                 const float* __restrict__ b1,
                                                 const float* __restrict__ W2,
                                                 const float* __restrict__ b2,
                                                 float* __restrict__ h, int relu_out) {
    __shared__ float sW2[64 * 64];
    __shared__ float4 stv[4][16];

    // stage W2 (vectorized)
    {
        const float4* W4 = reinterpret_cast<const float4*>(W2);
        float4* s4 = reinterpret_cast<float4*>(sW2);
        #pragma unroll
        for (int i = 0; i < 4; ++i)
            s4[threadIdx.x + i * 256] = W4[threadIdx.x + i * 256];
    }
    __syncthreads();

    int wid  = threadIdx.x >> 6;
    int lane = threadIdx.x & 63;
    int e4   = lane >> 4;       // edge sub-group 0..3
    int c16  = lane & 15;       // float4 channel chunk 0..15

    const float4* y4 = reinterpret_cast<const float4*>(y);
    const float*  stf = reinterpret_cast<const float*>(&stv[wid][0]);
    float4 b1v = reinterpret_cast<const float4*>(b1)[c16];
    float  b2v = b2[lane];

    #pragma unroll 1
    for (int t = 0; t < 4; ++t) {
        int node = blockIdx.x * NPB + wid * 4 + t;

        int start = row_ptr[node];
        int end   = row_ptr[node + 1];

        float4 acc = make_float4(0.f, 0.f, 0.f, 0.f);
        if (e4 == 0) acc = y4[(size_t)node * 16 + c16];   // self term

        int base = start;
        // main: 16 edges per iteration, 4 row-loads in flight per lane-group
        for (; base + 16 <= end; base += 16) {
            int i0 = col_idx[base + e4];
            int i1 = col_idx[base + 4 + e4];
            int i2 = col_idx[base + 8 + e4];
            int i3 = col_idx[base + 12 + e4];
            float4 v0 = y4[(size_t)i0 * 16 + c16];
            float4 v1 = y4[(size_t)i1 * 16 + c16];
            float4 v2 = y4[(size_t)i2 * 16 + c16];
            float4 v3 = y4[(size_t)i3 * 16 + c16];
            acc.x += v0.x + v1.x + v2.x + v3.x;
            acc.y += v0.y + v1.y + v2.y + v3.y;
            acc.z += v0.z + v1.z + v2.z + v3.z;
            acc.w += v0.w + v1.w + v2.w + v3.w;
        }
        // tail: rem < 16, straight-line predicated (loads stay in flight)
        {
            float4 z = make_float4(0.f, 0.f, 0.f, 0.f);
            float4 v0 = z, v1 = z, v2 = z, v3 = z;
            if (base + e4 < end)      v0 = y4[(size_t)col_idx[base + e4] * 16 + c16];
            if (base + 4 + e4 < end)  v1 = y4[(size_t)col_idx[base + 4 + e4] * 16 + c16];
            if (base + 8 + e4 < end)  v2 = y4[(size_t)col_idx[base + 8 + e4] * 16 + c16];
            if (base + 12 + e4 < end) v3 = y4[(size_t)col_idx[base + 12 + e4] * 16 + c16];
            acc.x += v0.x + v1.x + v2.x + v3.x;
            acc.y += v0.y + v1.y + v2.y + v3.y;
            acc.z += v0.z + v1.z + v2.z + v3.z;
            acc.w += v0.w + v1.w + v2.w + v3.w;
        }

        // reduce across the 4 edge groups (lanes differing in bits 4,5)
        #pragma unroll
        for (int m = 16; m <= 32; m <<= 1) {
            acc.x += __shfl_xor(acc.x, m);
            acc.y += __shfl_xor(acc.y, m);
            acc.z += __shfl_xor(acc.z, m);
            acc.w += __shfl_xor(acc.w, m);
        }

        // bias + relu, publish to wave-private st (no barrier: same-wave LDS dep)
        if (e4 == 0) {
            float4 tv;
            tv.x = fmaxf(acc.x + b1v.x, 0.0f);
            tv.y = fmaxf(acc.y + b1v.y, 0.0f);
            tv.z = fmaxf(acc.z + b1v.z, 0.0f);
            tv.w = fmaxf(acc.w + b1v.w, 0.0f);
            stv[wid][c16] = tv;
        }

        // GEMM2: u[lane] = b2[lane] + sum_k st[k] * W2[k][lane]
        float u = b2v;
        #pragma unroll 16
        for (int k = 0; k < 64; ++k)
            u = fmaf(stf[k], sW2[k * 64 + lane], u);
        if (relu_out) u = fmaxf(u, 0.0f);
        h[(size_t)node * 64 + lane] = u;
    }
}

// ---------------- pooling: segment mean (batch is sorted) ----------------
// wave per 64-node chunk; batch ids shfl-broadcast; 8 row-loads in flight.

__global__ __launch_bounds__(256) void pool_kernel(const float* __restrict__ h,
                                                   const int* __restrict__ batch,
                                                   float* __restrict__ pool,
                                                   float* __restrict__ counts, int n) {
    int gwave = (blockIdx.x * 256 + threadIdx.x) >> 6;
    int lane  = threadIdx.x & 63;
    int s = gwave * 64;
    if (s >= n) return;
    int nhere = min(64, n - s);

    int bv = (s + lane < n) ? batch[s + lane] : -1;
    int cur = __shfl(bv, 0);
    float acc = 0.0f, cnt = 0.0f;

    #pragma unroll 1
    for (int i0 = 0; i0 < 64; i0 += 8) {
        float v[8];
        #pragma unroll
        for (int j = 0; j < 8; ++j) {
            int i = i0 + j;
            v[j] = (i < nhere) ? h[(size_t)(s + i) * 64 + lane] : 0.0f;
        }
        #pragma unroll
        for (int j = 0; j < 8; ++j) {
            int i = i0 + j;
            if (i < nhere) {
                int g = __shfl(bv, i);
                if (g != cur) {   // wave-uniform, rare
                    atomicAdd(&pool[cur * 64 + lane], acc);
                    if (lane == 0) atomicAdd(&counts[cur], cnt);
                    cur = g; acc = 0.0f; cnt = 0.0f;
                }
                acc += v[j];
                cnt += 1.0f;
            }
        }
    }
    atomicAdd(&pool[cur * 64 + lane], acc);
    if (lane == 0) atomicAdd(&counts[cur], cnt);
}

// ---------------- head: pooled @ fc1 + b, @ pred + b, sigmoid ----------------

__global__ void head_kernel(const float* __restrict__ pool, const float* __restrict__ counts,
                            const float* __restrict__ fc1_W, const float* __restrict__ fc1_b,
                            const float* __restrict__ pred_W, const float* __restrict__ pred_b,
                            float* __restrict__ out) {
    int g = blockIdx.x;
    int t = threadIdx.x;  // 64 threads; lanes >= 32 idle for the dot
    float s = 0.0f;
    if (t < 32) {
        float cnt = fmaxf(counts[g], 1.0f);
        float inv = 1.0f / cnt;
        float f = fc1_b[t];
        #pragma unroll
        for (int k = 0; k < 64; ++k)
            f = fmaf(pool[g * 64 + k] * inv, fc1_W[k * 32 + t], f);
        s = f * pred_W[t];
    }
    #pragma unroll
    for (int off = 32; off > 0; off >>= 1) s += __shfl_down(s, off);
    if (t == 0) out[g] = 1.0f / (1.0f + expf(-(s + pred_b[0])));
}

// ---------------- launch ----------------

extern "C" void kernel_launch(void* const* d_in, const int* in_sizes, int n_in,
                              void* d_out, int out_size, void* d_ws, size_t ws_size,
                              hipStream_t stream) {
    const float* x      = (const float*)d_in[0];
    const int*   e_src  = (const int*)d_in[1];               // edge_index[0]
    const int*   e_dst  = ((const int*)d_in[1]) + N_EDGES;   // edge_index[1]
    const int*   batch  = (const int*)d_in[2];
    const float* c1_W1 = (const float*)d_in[3];
    const float* c1_b1 = (const float*)d_in[4];
    const float* c1_W2 = (const float*)d_in[5];
    const float* c1_b2 = (const float*)d_in[6];
    const float* c2_W1 = (const float*)d_in[7];
    const float* c2_b1 = (const float*)d_in[8];
    const float* c2_W2 = (const float*)d_in[9];
    const float* c2_b2 = (const float*)d_in[10];
    const float* c3_W1 = (const float*)d_in[11];
    const float* c3_b1 = (const float*)d_in[12];
    const float* c3_W2 = (const float*)d_in[13];
    const float* c3_b2 = (const float*)d_in[14];
    const float* fc1_W = (const float*)d_in[15];
    const float* fc1_b = (const float*)d_in[16];
    const float* predW = (const float*)d_in[17];
    const float* predb = (const float*)d_in[18];
    float* out = (float*)d_out;

    // workspace carve-up (aligned to 256B)
    char* ws = (char*)d_ws;
    size_t off = 0;
    auto carve = [&](size_t bytes) {
        char* p = ws + off;
        off += (bytes + 255) & ~(size_t)255;
        return p;
    };
    float* y        = (float*)carve((size_t)N_NODES * 64 * 4);
    float* h        = (float*)carve((size_t)N_NODES * 64 * 4);
    int*   row_ptr  = (int*)carve(((size_t)N_NODES + 1) * 4);
    int*   col_idx  = (int*)carve((size_t)N_EDGES * 4);
    int*   bucketCnt = (int*)carve(NB * 4);
    int*   bucketOff = (int*)carve((NB + 1) * 4);
    int*   bucketCur = (int*)carve(NB * 4);
    float* pool     = (float*)carve(N_GRAPHS * 64 * 4);
    float* counts   = (float*)carve(N_GRAPHS * 4);
    (void)ws_size; (void)n_in; (void)in_sizes; (void)out_size;

    // sorted edge array (12.8MB) aliases y (25.6MB): dead before first project
    uint2* sorted = (uint2*)y;

    const int GIN_BLOCKS  = (N_NODES + NPB - 1) / NPB; // 6250 (16 nodes/block)
    const int PROJ_BLOCKS = (N_NODES + 63) / 64;       // 1563 (64 nodes/block)
    const int POOL_BLOCKS = (N_NODES + 255) / 256;     // 391 (4 waves x 64 nodes)

    // zero accumulators
    hipMemsetAsync(bucketCnt, 0, NB * 4, stream);
    hipMemsetAsync(pool, 0, (N_GRAPHS * 64 + N_GRAPHS) * 4 + 256, stream);

    // CSR build via bucket semi-sort (reused for all 3 layers)
    bucket_count<<<P12_BLOCKS, 256, 0, stream>>>(e_dst, bucketCnt, N_EDGES);
    bucket_scan<<<1, 256, 0, stream>>>(bucketCnt, bucketOff, bucketCur, row_ptr);
    bucket_scatter<<<P12_BLOCKS, 256, 0, stream>>>(e_src, e_dst, bucketCur, sorted, N_EDGES);
    bucket_csr<<<NB, 256, 0, stream>>>(sorted, bucketOff, row_ptr, col_idx);

    // layer 1 (project 128->64 BEFORE aggregation: linearity of W1)
    project_kernel<EMB><<<PROJ_BLOCKS, 256, 0, stream>>>(x, c1_W1, y);
    gin_layer<<<GIN_BLOCKS, 256, 0, stream>>>(y, row_ptr, col_idx, c1_b1, c1_W2, c1_b2, h, 1);

    // layer 2
    project_kernel<HID><<<PROJ_BLOCKS, 256, 0, stream>>>(h, c2_W1, y);
    gin_layer<<<GIN_BLOCKS, 256, 0, stream>>>(y, row_ptr, col_idx, c2_b1, c2_W2, c2_b2, h, 1);

    // layer 3 (no output relu)
    project_kernel<HID><<<PROJ_BLOCKS, 256, 0, stream>>>(h, c3_W1, y);
    gin_layer<<<GIN_BLOCKS, 256, 0, stream>>>(y, row_ptr, col_idx, c3_b1, c3_W2, c3_b2, h, 0);

    // pool + head
    pool_kernel<<<POOL_BLOCKS, 256, 0, stream>>>(h, batch, pool, counts, N_NODES);
    head_kernel<<<N_GRAPHS, 64, 0, stream>>>(pool, counts, fc1_W, fc1_b, predW, predb, out);
}

// Round 6
// 327.876 us; speedup vs baseline: 3.5036x; 1.1078x over previous
//
#include <hip/hip_runtime.h>
#include <hip/hip_fp16.h>
#include <math.h>

#define N_NODES 100000
#define N_EDGES 1600000
#define N_GRAPHS 64
#define EMB 128
#define HID 64

#define BUCKET_BITS 9
#define BUCKET_SZ   512
#define NB          196   // ceil(N_NODES / 512)
#define EPB         4096  // edges per block in bucket passes
#define P12_BLOCKS  391   // ceil(N_EDGES / 4096)

// ---------------- block-wide exclusive scan over 256 threads ----------------

__device__ inline int block_scan_excl_256(int v) {
    int t = threadIdx.x;
    int lane = t & 63, wid = t >> 6;
    int incl = v;
    #pragma unroll
    for (int off = 1; off < 64; off <<= 1) {
        int u = __shfl_up(incl, off);
        if (lane >= off) incl += u;
    }
    __shared__ int wsum[4];
    if (lane == 63) wsum[wid] = incl;
    __syncthreads();
    int woff = 0;
    for (int w = 0; w < wid; ++w) woff += wsum[w];
    __syncthreads();
    return woff + incl - v;
}

// ---------------- CSR build via bucket semi-sort ----------------

__global__ __launch_bounds__(256) void bucket_count(const int* __restrict__ dst,
                                                    int* __restrict__ bucketCnt, int e) {
    __shared__ int bins[NB];
    for (int i = threadIdx.x; i < NB; i += 256) bins[i] = 0;
    __syncthreads();
    int base = blockIdx.x * EPB;
    #pragma unroll
    for (int j = 0; j < 16; ++j) {
        int i = base + j * 256 + threadIdx.x;
        if (i < e) atomicAdd(&bins[dst[i] >> BUCKET_BITS], 1);
    }
    __syncthreads();
    for (int i = threadIdx.x; i < NB; i += 256)
        if (bins[i]) atomicAdd(&bucketCnt[i], bins[i]);
}

__global__ void bucket_scan(const int* __restrict__ bucketCnt, int* __restrict__ bucketOff,
                            int* __restrict__ bucketCur, int* __restrict__ row_ptr) {
    int t = threadIdx.x;
    int v = (t < NB) ? bucketCnt[t] : 0;
    int excl = block_scan_excl_256(v);
    if (t < NB) { bucketOff[t] = excl; bucketCur[t] = excl; }
    if (t == 0) { bucketOff[NB] = N_EDGES; row_ptr[N_NODES] = N_EDGES; }
}

__global__ __launch_bounds__(256) void bucket_scatter(const int* __restrict__ src,
                                                      const int* __restrict__ dst,
                                                      int* __restrict__ bucketCur,
                                                      uint2* __restrict__ sorted, int e) {
    __shared__ int bins[NB];
    __shared__ int lbase[NB];
    __shared__ int gbase[NB];
    __shared__ int cur[NB];
    __shared__ uint2 stage[EPB];   // 32 KB

    for (int i = threadIdx.x; i < NB; i += 256) bins[i] = 0;
    __syncthreads();

    int base = blockIdx.x * EPB;
    #pragma unroll
    for (int j = 0; j < 16; ++j) {
        int i = base + j * 256 + threadIdx.x;
        if (i < e) atomicAdd(&bins[dst[i] >> BUCKET_BITS], 1);
    }
    __syncthreads();

    int t = threadIdx.x;
    int v = (t < NB) ? bins[t] : 0;
    int excl = block_scan_excl_256(v);
    if (t < NB) {
        lbase[t] = excl;
        cur[t]   = excl;
        gbase[t] = v ? atomicAdd(&bucketCur[t], v) : 0;
    }
    __syncthreads();

    #pragma unroll
    for (int j = 0; j < 16; ++j) {
        int i = base + j * 256 + threadIdx.x;
        if (i < e) {
            int d = dst[i], s = src[i];
            int p = atomicAdd(&cur[d >> BUCKET_BITS], 1);
            stage[p] = make_uint2((unsigned)d, (unsigned)s);
        }
    }
    __syncthreads();

    int cnt = min(EPB, e - base);
    for (int idx = threadIdx.x; idx < cnt; idx += 256) {
        uint2 ed = stage[idx];
        int b = (int)(ed.x >> BUCKET_BITS);
        sorted[gbase[b] + (idx - lbase[b])] = ed;   // contiguous runs per bucket
    }
}

__global__ __launch_bounds__(256) void bucket_csr(const uint2* __restrict__ sorted,
                                                  const int* __restrict__ bucketOff,
                                                  int* __restrict__ row_ptr,
                                                  int* __restrict__ col_idx) {
    int b  = blockIdx.x;
    int S  = bucketOff[b];
    int Eb = bucketOff[b + 1];
    int n0 = b << BUCKET_BITS;
    int nNodes = min(BUCKET_SZ, N_NODES - n0);

    __shared__ int cnt[BUCKET_SZ];
    __shared__ int excl[BUCKET_SZ];
    __shared__ int cur[BUCKET_SZ];

    for (int i = threadIdx.x; i < BUCKET_SZ; i += 256) cnt[i] = 0;
    __syncthreads();

    for (int idx = S + threadIdx.x; idx < Eb; idx += 256)
        atomicAdd(&cnt[(int)sorted[idx].x - n0], 1);
    __syncthreads();

    int t = threadIdx.x;
    int v = cnt[2 * t] + cnt[2 * t + 1];
    int pe = block_scan_excl_256(v);
    excl[2 * t]     = pe;
    excl[2 * t + 1] = pe + cnt[2 * t];
    __syncthreads();

    for (int i = threadIdx.x; i < nNodes; i += 256)
        row_ptr[n0 + i] = S + excl[i];
    for (int i = threadIdx.x; i < BUCKET_SZ; i += 256) cur[i] = excl[i];
    __syncthreads();

    for (int idx = S + threadIdx.x; idx < Eb; idx += 256) {
        uint2 ed = sorted[idx];
        int ln = (int)ed.x - n0;
        int slot = S + atomicAdd(&cur[ln], 1);
        col_idx[slot] = (int)ed.y;
    }
}

// ---------------- fp16 helpers ----------------

__device__ inline float4 half4_to_float4(ushort4 u) {
    union { ushort2 us; __half2 h2; } a, b;
    a.us = make_ushort2(u.x, u.y);
    b.us = make_ushort2(u.z, u.w);
    float2 fa = __half22float2(a.h2);
    float2 fb = __half22float2(b.h2);
    return make_float4(fa.x, fa.y, fb.x, fb.y);
}

// ---------------- dense projection: y = h @ W (Din -> 64), fp16 out ----------------
// lane = node (64 nodes/wave), wave computes a 16-channel output slice.
// W read at wave-uniform addresses (scalar pipe), reused by all 64 lanes.

template <int DIN>
__global__ __launch_bounds__(256) void project_kernel(const float* __restrict__ h,
                                                      const float* __restrict__ W,
                                                      ushort* __restrict__ y) {
    int wid  = threadIdx.x >> 6;                 // 0..3 -> out-channel group
    int lane = threadIdx.x & 63;                 // node within tile
    int node = blockIdx.x * 64 + lane;
    bool valid = node < N_NODES;
    const float4* row = reinterpret_cast<const float4*>(h + (size_t)(valid ? node : 0) * DIN);
    int ob = __builtin_amdgcn_readfirstlane(wid * 16);   // force scalar uniformity

    float acc[16];
    #pragma unroll
    for (int o = 0; o < 16; ++o) acc[o] = 0.0f;

    #pragma unroll 4
    for (int k4 = 0; k4 < DIN / 4; ++k4) {
        float4 a = row[k4];
        #pragma unroll
        for (int kk = 0; kk < 4; ++kk) {
            int k = k4 * 4 + kk;
            float av = (kk == 0) ? a.x : (kk == 1) ? a.y : (kk == 2) ? a.z : a.w;
            const float* wr = W + k * 64 + ob;   // uniform address -> s_load
            #pragma unroll
            for (int o = 0; o < 16; ++o)
                acc[o] = fmaf(av, wr[o], acc[o]);
        }
    }

    if (valid) {
        union { uint4 v; ushort u[8]; } p0, p1;
        #pragma unroll
        for (int i = 0; i < 8; ++i)
            p0.u[i] = __half_as_ushort(__float2half_rn(acc[i]));
        #pragma unroll
        for (int i = 0; i < 8; ++i)
            p1.u[i] = __half_as_ushort(__float2half_rn(acc[8 + i]));
        uint4* yr = reinterpret_cast<uint4*>(y + (size_t)node * 64 + ob);  // 16B aligned
        yr[0] = p0.v;
        yr[1] = p1.v;
    }
}

// ---------------- fused layer: gather-sum(fp16 rows) + bias + relu + GEMM2 ----------------
// lane = (e4 = lane>>4, c16 = lane&15). 16 lanes x ushort4 (8B) = one 128B fp16
// row per group; 4 rows per load instruction, 16 rows in flight in main loop.

#define NPB 16  // nodes per block

__global__ __launch_bounds__(256) void gin_layer(const ushort* __restrict__ y,
                                                 const int* __restrict__ row_ptr,
                                                 const int* __restrict__ col_idx,
                                                 const float* __restrict__ b1,
                                                 const float* __restrict__ W2,
                                                 const float* __restrict__ b2,
                                                 float* __restrict__ h, int relu_out) {
    __shared__ float sW2[64 * 64];
    __shared__ float4 stv[4][16];

    // stage W2 (vectorized)
    {
        const float4* W4 = reinterpret_cast<const float4*>(W2);
        float4* s4 = reinterpret_cast<float4*>(sW2);
        #pragma unroll
        for (int i = 0; i < 4; ++i)
            s4[threadIdx.x + i * 256] = W4[threadIdx.x + i * 256];
    }
    __syncthreads();

    int wid  = threadIdx.x >> 6;
    int lane = threadIdx.x & 63;
    int e4   = lane >> 4;       // edge sub-group 0..3
    int c16  = lane & 15;       // channel chunk (4 halves) 0..15

    const ushort4* y4 = reinterpret_cast<const ushort4*>(y);  // row stride = 16 chunks
    const float*  stf = reinterpret_cast<const float*>(&stv[wid][0]);
    float4 b1v = reinterpret_cast<const float4*>(b1)[c16];
    float  b2v = b2[lane];

    #pragma unroll 1
    for (int t = 0; t < 4; ++t) {
        int node = blockIdx.x * NPB + wid * 4 + t;

        int start = row_ptr[node];
        int end   = row_ptr[node + 1];

        float4 acc = make_float4(0.f, 0.f, 0.f, 0.f);
        if (e4 == 0) {
            float4 sv = half4_to_float4(y4[(size_t)node * 16 + c16]);   // self term
            acc = sv;
        }

        int base = start;
        // main: 16 edges per iteration, 4 row-loads in flight per lane-group
        for (; base + 16 <= end; base += 16) {
            int i0 = col_idx[base + e4];
            int i1 = col_idx[base + 4 + e4];
            int i2 = col_idx[base + 8 + e4];
            int i3 = col_idx[base + 12 + e4];
            ushort4 u0 = y4[(size_t)i0 * 16 + c16];
            ushort4 u1 = y4[(size_t)i1 * 16 + c16];
            ushort4 u2 = y4[(size_t)i2 * 16 + c16];
            ushort4 u3 = y4[(size_t)i3 * 16 + c16];
            float4 v0 = half4_to_float4(u0);
            float4 v1 = half4_to_float4(u1);
            float4 v2 = half4_to_float4(u2);
            float4 v3 = half4_to_float4(u3);
            acc.x += v0.x + v1.x + v2.x + v3.x;
            acc.y += v0.y + v1.y + v2.y + v3.y;
            acc.z += v0.z + v1.z + v2.z + v3.z;
            acc.w += v0.w + v1.w + v2.w + v3.w;
        }
        // tail: rem < 16, straight-line predicated (loads stay in flight)
        {
            ushort4 z = make_ushort4(0, 0, 0, 0);
            ushort4 u0 = z, u1 = z, u2 = z, u3 = z;
            if (base + e4 < end)      u0 = y4[(size_t)col_idx[base + e4] * 16 + c16];
            if (base + 4 + e4 < end)  u1 = y4[(size_t)col_idx[base + 4 + e4] * 16 + c16];
            if (base + 8 + e4 < end)  u2 = y4[(size_t)col_idx[base + 8 + e4] * 16 + c16];
            if (base + 12 + e4 < end) u3 = y4[(size_t)col_idx[base + 12 + e4] * 16 + c16];
            float4 v0 = half4_to_float4(u0);
            float4 v1 = half4_to_float4(u1);
            float4 v2 = half4_to_float4(u2);
            float4 v3 = half4_to_float4(u3);
            acc.x += v0.x + v1.x + v2.x + v3.x;
            acc.y += v0.y + v1.y + v2.y + v3.y;
            acc.z += v0.z + v1.z + v2.z + v3.z;
            acc.w += v0.w + v1.w + v2.w + v3.w;
        }

        // reduce across the 4 edge groups (lanes differing in bits 4,5)
        #pragma unroll
        for (int m = 16; m <= 32; m <<= 1) {
            acc.x += __shfl_xor(acc.x, m);
            acc.y += __shfl_xor(acc.y, m);
            acc.z += __shfl_xor(acc.z, m);
            acc.w += __shfl_xor(acc.w, m);
        }

        // bias + relu, publish to wave-private st (no barrier: same-wave LDS dep)
        if (e4 == 0) {
            float4 tv;
            tv.x = fmaxf(acc.x + b1v.x, 0.0f);
            tv.y = fmaxf(acc.y + b1v.y, 0.0f);
            tv.z = fmaxf(acc.z + b1v.z, 0.0f);
            tv.w = fmaxf(acc.w + b1v.w, 0.0f);
            stv[wid][c16] = tv;
        }

        // GEMM2: u[lane] = b2[lane] + sum_k st[k] * W2[k][lane]
        float u = b2v;
        #pragma unroll 16
        for (int k = 0; k < 64; ++k)
            u = fmaf(stf[k], sW2[k * 64 + lane], u);
        if (relu_out) u = fmaxf(u, 0.0f);
        h[(size_t)node * 64 + lane] = u;
    }
}

// ---------------- pooling: segment mean (batch is sorted) ----------------
// wave per 64-node chunk; batch ids shfl-broadcast; 8 row-loads in flight.

__global__ __launch_bounds__(256) void pool_kernel(const float* __restrict__ h,
                                                   const int* __restrict__ batch,
                                                   float* __restrict__ pool,
                                                   float* __restrict__ counts, int n) {
    int gwave = (blockIdx.x * 256 + threadIdx.x) >> 6;
    int lane  = threadIdx.x & 63;
    int s = gwave * 64;
    if (s >= n) return;
    int nhere = min(64, n - s);

    int bv = (s + lane < n) ? batch[s + lane] : -1;
    int cur = __shfl(bv, 0);
    float acc = 0.0f, cnt = 0.0f;

    #pragma unroll 1
    for (int i0 = 0; i0 < 64; i0 += 8) {
        float v[8];
        #pragma unroll
        for (int j = 0; j < 8; ++j) {
            int i = i0 + j;
            v[j] = (i < nhere) ? h[(size_t)(s + i) * 64 + lane] : 0.0f;
        }
        #pragma unroll
        for (int j = 0; j < 8; ++j) {
            int i = i0 + j;
            if (i < nhere) {
                int g = __shfl(bv, i);
                if (g != cur) {   // wave-uniform, rare
                    atomicAdd(&pool[cur * 64 + lane], acc);
                    if (lane == 0) atomicAdd(&counts[cur], cnt);
                    cur = g; acc = 0.0f; cnt = 0.0f;
                }
                acc += v[j];
                cnt += 1.0f;
            }
        }
    }
    atomicAdd(&pool[cur * 64 + lane], acc);
    if (lane == 0) atomicAdd(&counts[cur], cnt);
}

// ---------------- head: pooled @ fc1 + b, @ pred + b, sigmoid ----------------

__global__ void head_kernel(const float* __restrict__ pool, const float* __restrict__ counts,
                            const float* __restrict__ fc1_W, const float* __restrict__ fc1_b,
                            const float* __restrict__ pred_W, const float* __restrict__ pred_b,
                            float* __restrict__ out) {
    int g = blockIdx.x;
    int t = threadIdx.x;  // 64 threads; lanes >= 32 idle for the dot
    float s = 0.0f;
    if (t < 32) {
        float cnt = fmaxf(counts[g], 1.0f);
        float inv = 1.0f / cnt;
        float f = fc1_b[t];
        #pragma unroll
        for (int k = 0; k < 64; ++k)
            f = fmaf(pool[g * 64 + k] * inv, fc1_W[k * 32 + t], f);
        s = f * pred_W[t];
    }
    #pragma unroll
    for (int off = 32; off > 0; off >>= 1) s += __shfl_down(s, off);
    if (t == 0) out[g] = 1.0f / (1.0f + expf(-(s + pred_b[0])));
}

// ---------------- launch ----------------

extern "C" void kernel_launch(void* const* d_in, const int* in_sizes, int n_in,
                              void* d_out, int out_size, void* d_ws, size_t ws_size,
                              hipStream_t stream) {
    const float* x      = (const float*)d_in[0];
    const int*   e_src  = (const int*)d_in[1];               // edge_index[0]
    const int*   e_dst  = ((const int*)d_in[1]) + N_EDGES;   // edge_index[1]
    const int*   batch  = (const int*)d_in[2];
    const float* c1_W1 = (const float*)d_in[3];
    const float* c1_b1 = (const float*)d_in[4];
    const float* c1_W2 = (const float*)d_in[5];
    const float* c1_b2 = (const float*)d_in[6];
    const float* c2_W1 = (const float*)d_in[7];
    const float* c2_b1 = (const float*)d_in[8];
    const float* c2_W2 = (const float*)d_in[9];
    const float* c2_b2 = (const float*)d_in[10];
    const float* c3_W1 = (const float*)d_in[11];
    const float* c3_b1 = (const float*)d_in[12];
    const float* c3_W2 = (const float*)d_in[13];
    const float* c3_b2 = (const float*)d_in[14];
    const float* fc1_W = (const float*)d_in[15];
    const float* fc1_b = (const float*)d_in[16];
    const float* predW = (const float*)d_in[17];
    const float* predb = (const float*)d_in[18];
    float* out = (float*)d_out;

    // workspace carve-up (aligned to 256B)
    char* ws = (char*)d_ws;
    size_t off = 0;
    auto carve = [&](size_t bytes) {
        char* p = ws + off;
        off += (bytes + 255) & ~(size_t)255;
        return p;
    };
    ushort* y       = (ushort*)carve((size_t)N_NODES * 64 * 2);   // fp16 payload, 12.8 MB
    float* h        = (float*)carve((size_t)N_NODES * 64 * 4);
    int*   row_ptr  = (int*)carve(((size_t)N_NODES + 1) * 4);
    int*   col_idx  = (int*)carve((size_t)N_EDGES * 4);
    int*   bucketCnt = (int*)carve(NB * 4);
    int*   bucketOff = (int*)carve((NB + 1) * 4);
    int*   bucketCur = (int*)carve(NB * 4);
    float* pool     = (float*)carve(N_GRAPHS * 64 * 4);
    float* counts   = (float*)carve(N_GRAPHS * 4);
    // sorted edge array (12.8MB): separate carve (y is only 12.8MB now, same size
    // but lifetimes overlap with nothing else -- keep aliasing y: sorted is dead
    // before the first project writes y)
    uint2* sorted = (uint2*)y;
    (void)ws_size; (void)n_in; (void)in_sizes; (void)out_size;

    const int GIN_BLOCKS  = (N_NODES + NPB - 1) / NPB; // 6250 (16 nodes/block)
    const int PROJ_BLOCKS = (N_NODES + 63) / 64;       // 1563 (64 nodes/block)
    const int POOL_BLOCKS = (N_NODES + 255) / 256;     // 391 (4 waves x 64 nodes)

    // zero accumulators
    hipMemsetAsync(bucketCnt, 0, NB * 4, stream);
    hipMemsetAsync(pool, 0, (N_GRAPHS * 64 + N_GRAPHS) * 4 + 256, stream);

    // CSR build via bucket semi-sort (reused for all 3 layers)
    bucket_count<<<P12_BLOCKS, 256, 0, stream>>>(e_dst, bucketCnt, N_EDGES);
    bucket_scan<<<1, 256, 0, stream>>>(bucketCnt, bucketOff, bucketCur, row_ptr);
    bucket_scatter<<<P12_BLOCKS, 256, 0, stream>>>(e_src, e_dst, bucketCur, sorted, N_EDGES);
    bucket_csr<<<NB, 256, 0, stream>>>(sorted, bucketOff, row_ptr, col_idx);

    // layer 1 (project 128->64 BEFORE aggregation: linearity of W1)
    project_kernel<EMB><<<PROJ_BLOCKS, 256, 0, stream>>>(x, c1_W1, y);
    gin_layer<<<GIN_BLOCKS, 256, 0, stream>>>(y, row_ptr, col_idx, c1_b1, c1_W2, c1_b2, h, 1);

    // layer 2
    project_kernel<HID><<<PROJ_BLOCKS, 256, 0, stream>>>(h, c2_W1, y);
    gin_layer<<<GIN_BLOCKS, 256, 0, stream>>>(y, row_ptr, col_idx, c2_b1, c2_W2, c2_b2, h, 1);

    // layer 3 (no output relu)
    project_kernel<HID><<<PROJ_BLOCKS, 256, 0, stream>>>(h, c3_W1, y);
    gin_layer<<<GIN_BLOCKS, 256, 0, stream>>>(y, row_ptr, col_idx, c3_b1, c3_W2, c3_b2, h, 0);

    // pool + head
    pool_kernel<<<POOL_BLOCKS, 256, 0, stream>>>(h, batch, pool, counts, N_NODES);
    head_kernel<<<N_GRAPHS, 64, 0, stream>>>(pool, counts, fc1_W, fc1_b, predW, predb, out);
}

// Round 7
// 292.591 us; speedup vs baseline: 3.9261x; 1.1206x over previous
//
#include <hip/hip_runtime.h>
#include <hip/hip_fp16.h>
#include <math.h>

#define N_NODES 100000
#define N_EDGES 1600000
#define N_GRAPHS 64
#define EMB 128
#define HID 64

#define BUCKET_BITS 9
#define BUCKET_SZ   512
#define NB          196   // ceil(N_NODES / 512)
#define EPB         4096  // edges per block in bucket passes
#define P12_BLOCKS  391   // ceil(N_EDGES / 4096)

// ---------------- fp16 packed helpers ----------------

typedef _Float16 half2_t __attribute__((ext_vector_type(2)));

__device__ inline unsigned hadd2u(unsigned a, unsigned b) {
    __half2 ha = __builtin_bit_cast(__half2, a);
    __half2 hb = __builtin_bit_cast(__half2, b);
    return __builtin_bit_cast(unsigned, __hadd2(ha, hb));
}

// relu on two packed halves, branchless (sign-mask); -0 -> +0
__device__ inline unsigned relu2(unsigned v) {
    unsigned m = (v >> 15) & 0x00010001u;
    return v & ~(m * 0xFFFFu);
}

__device__ inline float fdot2h(unsigned a, unsigned b, float c) {
#if __has_builtin(__builtin_amdgcn_fdot2)
    half2_t ha = __builtin_bit_cast(half2_t, a);
    half2_t hb = __builtin_bit_cast(half2_t, b);
    return __builtin_amdgcn_fdot2(ha, hb, c, false);
#else
    __half2 ha = __builtin_bit_cast(__half2, a);
    __half2 hb = __builtin_bit_cast(__half2, b);
    float2 fa = __half22float2(ha);
    float2 fb = __half22float2(hb);
    return fmaf(fa.x, fb.x, fmaf(fa.y, fb.y, c));
#endif
}

__device__ inline unsigned pack2(float a, float b) {
    __half2 p = __floats2half2_rn(a, b);
    return __builtin_bit_cast(unsigned, p);
}

// ---------------- block-wide exclusive scan over 256 threads ----------------

__device__ inline int block_scan_excl_256(int v) {
    int t = threadIdx.x;
    int lane = t & 63, wid = t >> 6;
    int incl = v;
    #pragma unroll
    for (int off = 1; off < 64; off <<= 1) {
        int u = __shfl_up(incl, off);
        if (lane >= off) incl += u;
    }
    __shared__ int wsum[4];
    if (lane == 63) wsum[wid] = incl;
    __syncthreads();
    int woff = 0;
    for (int w = 0; w < wid; ++w) woff += wsum[w];
    __syncthreads();
    return woff + incl - v;
}

// ---------------- CSR build via bucket semi-sort ----------------

__global__ __launch_bounds__(256) void bucket_count(const int* __restrict__ dst,
                                                    int* __restrict__ bucketCnt, int e) {
    __shared__ int bins[NB];
    for (int i = threadIdx.x; i < NB; i += 256) bins[i] = 0;
    __syncthreads();
    int base = blockIdx.x * EPB;
    #pragma unroll
    for (int j = 0; j < 16; ++j) {
        int i = base + j * 256 + threadIdx.x;
        if (i < e) atomicAdd(&bins[dst[i] >> BUCKET_BITS], 1);
    }
    __syncthreads();
    for (int i = threadIdx.x; i < NB; i += 256)
        if (bins[i]) atomicAdd(&bucketCnt[i], bins[i]);
}

__global__ void bucket_scan(const int* __restrict__ bucketCnt, int* __restrict__ bucketOff,
                            int* __restrict__ bucketCur, int* __restrict__ row_ptr) {
    int t = threadIdx.x;
    int v = (t < NB) ? bucketCnt[t] : 0;
    int excl = block_scan_excl_256(v);
    if (t < NB) { bucketOff[t] = excl; bucketCur[t] = excl; }
    if (t == 0) { bucketOff[NB] = N_EDGES; row_ptr[N_NODES] = N_EDGES; }
}

__global__ __launch_bounds__(256) void bucket_scatter(const int* __restrict__ src,
                                                      const int* __restrict__ dst,
                                                      int* __restrict__ bucketCur,
                                                      uint2* __restrict__ sorted, int e) {
    __shared__ int bins[NB];
    __shared__ int lbase[NB];
    __shared__ int gbase[NB];
    __shared__ int cur[NB];
    __shared__ uint2 stage[EPB];   // 32 KB

    for (int i = threadIdx.x; i < NB; i += 256) bins[i] = 0;
    __syncthreads();

    int base = blockIdx.x * EPB;
    #pragma unroll
    for (int j = 0; j < 16; ++j) {
        int i = base + j * 256 + threadIdx.x;
        if (i < e) atomicAdd(&bins[dst[i] >> BUCKET_BITS], 1);
    }
    __syncthreads();

    int t = threadIdx.x;
    int v = (t < NB) ? bins[t] : 0;
    int excl = block_scan_excl_256(v);
    if (t < NB) {
        lbase[t] = excl;
        cur[t]   = excl;
        gbase[t] = v ? atomicAdd(&bucketCur[t], v) : 0;
    }
    __syncthreads();

    #pragma unroll
    for (int j = 0; j < 16; ++j) {
        int i = base + j * 256 + threadIdx.x;
        if (i < e) {
            int d = dst[i], s = src[i];
            int p = atomicAdd(&cur[d >> BUCKET_BITS], 1);
            stage[p] = make_uint2((unsigned)d, (unsigned)s);
        }
    }
    __syncthreads();

    int cnt = min(EPB, e - base);
    for (int idx = threadIdx.x; idx < cnt; idx += 256) {
        uint2 ed = stage[idx];
        int b = (int)(ed.x >> BUCKET_BITS);
        sorted[gbase[b] + (idx - lbase[b])] = ed;   // contiguous runs per bucket
    }
}

__global__ __launch_bounds__(256) void bucket_csr(const uint2* __restrict__ sorted,
                                                  const int* __restrict__ bucketOff,
                                                  int* __restrict__ row_ptr,
                                                  int* __restrict__ col_idx) {
    int b  = blockIdx.x;
    int S  = bucketOff[b];
    int Eb = bucketOff[b + 1];
    int n0 = b << BUCKET_BITS;
    int nNodes = min(BUCKET_SZ, N_NODES - n0);

    __shared__ int cnt[BUCKET_SZ];
    __shared__ int excl[BUCKET_SZ];
    __shared__ int cur[BUCKET_SZ];

    for (int i = threadIdx.x; i < BUCKET_SZ; i += 256) cnt[i] = 0;
    __syncthreads();

    for (int idx = S + threadIdx.x; idx < Eb; idx += 256)
        atomicAdd(&cnt[(int)sorted[idx].x - n0], 1);
    __syncthreads();

    int t = threadIdx.x;
    int v = cnt[2 * t] + cnt[2 * t + 1];
    int pe = block_scan_excl_256(v);
    excl[2 * t]     = pe;
    excl[2 * t + 1] = pe + cnt[2 * t];
    __syncthreads();

    for (int i = threadIdx.x; i < nNodes; i += 256)
        row_ptr[n0 + i] = S + excl[i];
    for (int i = threadIdx.x; i < BUCKET_SZ; i += 256) cur[i] = excl[i];
    __syncthreads();

    for (int idx = S + threadIdx.x; idx < Eb; idx += 256) {
        uint2 ed = sorted[idx];
        int ln = (int)ed.x - n0;
        int slot = S + atomicAdd(&cur[ln], 1);
        col_idx[slot] = (int)ed.y;
    }
}

// ---------------- dense projection: y = h @ W (Din -> 64), fp16 out ----------------
// lane = node (64 nodes/wave), wave computes a 16-channel output slice.
// W read at wave-uniform addresses (scalar pipe), reused by all 64 lanes.

template <int DIN>
__global__ __launch_bounds__(256) void project_kernel(const float* __restrict__ h,
                                                      const float* __restrict__ W,
                                                      ushort* __restrict__ y) {
    int wid  = threadIdx.x >> 6;                 // 0..3 -> out-channel group
    int lane = threadIdx.x & 63;                 // node within tile
    int node = blockIdx.x * 64 + lane;
    bool valid = node < N_NODES;
    const float4* row = reinterpret_cast<const float4*>(h + (size_t)(valid ? node : 0) * DIN);
    int ob = __builtin_amdgcn_readfirstlane(wid * 16);   // force scalar uniformity

    float acc[16];
    #pragma unroll
    for (int o = 0; o < 16; ++o) acc[o] = 0.0f;

    #pragma unroll 4
    for (int k4 = 0; k4 < DIN / 4; ++k4) {
        float4 a = row[k4];
        #pragma unroll
        for (int kk = 0; kk < 4; ++kk) {
            int k = k4 * 4 + kk;
            float av = (kk == 0) ? a.x : (kk == 1) ? a.y : (kk == 2) ? a.z : a.w;
            const float* wr = W + k * 64 + ob;   // uniform address -> s_load
            #pragma unroll
            for (int o = 0; o < 16; ++o)
                acc[o] = fmaf(av, wr[o], acc[o]);
        }
    }

    if (valid) {
        uint4 p0, p1;
        p0.x = pack2(acc[0], acc[1]);   p0.y = pack2(acc[2], acc[3]);
        p0.z = pack2(acc[4], acc[5]);   p0.w = pack2(acc[6], acc[7]);
        p1.x = pack2(acc[8], acc[9]);   p1.y = pack2(acc[10], acc[11]);
        p1.z = pack2(acc[12], acc[13]); p1.w = pack2(acc[14], acc[15]);
        uint4* yr = reinterpret_cast<uint4*>(y + (size_t)node * 64 + ob);  // 16B aligned
        yr[0] = p0;
        yr[1] = p1;
    }
}

// ---------------- fused layer: gather-sum(fp16, pk_add) + bias + relu + dot2-GEMM2 ----------------
// lane = (e4 = lane>>4, c16 = lane&15). 16 lanes x uint2 (8B, 4 halves) = one
// 128B fp16 row per group; 4 rows per load instruction, 16 rows in flight.
// Accumulate packed fp16 (v_pk_add_f16); GEMM2 with v_dot2_f32_f16 on fp16 W2.

#define NPB 16  // nodes per block

__global__ __launch_bounds__(256) void gin_layer(const ushort* __restrict__ y,
                                                 const int* __restrict__ row_ptr,
                                                 const int* __restrict__ col_idx,
                                                 const float* __restrict__ b1,
                                                 const float* __restrict__ W2,
                                                 const float* __restrict__ b2,
                                                 float* __restrict__ h, int relu_out) {
    __shared__ unsigned sW2p[32 * 64];   // packed half2 [k2][o], 8 KB
    __shared__ unsigned stp[4][32];      // packed st per wave (channels 2k2,2k2+1)

    // stage packed-fp16 W2: thread (k2b = t>>6, o = t&63), 8 k2 rows each
    {
        int o   = threadIdx.x & 63;
        int k2b = threadIdx.x >> 6;
        #pragma unroll
        for (int i = 0; i < 8; ++i) {
            int k2 = i * 4 + k2b;
            float a = W2[(2 * k2) * 64 + o];
            float b = W2[(2 * k2 + 1) * 64 + o];
            sW2p[k2 * 64 + o] = pack2(a, b);
        }
    }
    __syncthreads();

    int wid  = threadIdx.x >> 6;
    int lane = threadIdx.x & 63;
    int e4   = lane >> 4;       // edge sub-group 0..3
    int c16  = lane & 15;       // channel chunk (4 halves) 0..15

    const uint2* yp = reinterpret_cast<const uint2*>(y);  // row stride = 16 uint2
    float4 b1f = reinterpret_cast<const float4*>(b1)[c16];
    unsigned b1p0 = pack2(b1f.x, b1f.y);
    unsigned b1p1 = pack2(b1f.z, b1f.w);
    float b2v = b2[lane];

    #pragma unroll 1
    for (int t = 0; t < 4; ++t) {
        int node = blockIdx.x * NPB + wid * 4 + t;

        int start = row_ptr[node];
        int end   = row_ptr[node + 1];

        unsigned a0 = 0u, a1 = 0u;
        if (e4 == 0) {
            uint2 s = yp[(size_t)node * 16 + c16];   // self term (already packed fp16)
            a0 = s.x; a1 = s.y;
        }

        int base = start;
        // main: 16 edges per iteration, 4 row-loads in flight per lane-group
        for (; base + 16 <= end; base += 16) {
            int i0 = col_idx[base + e4];
            int i1 = col_idx[base + 4 + e4];
            int i2 = col_idx[base + 8 + e4];
            int i3 = col_idx[base + 12 + e4];
            uint2 u0 = yp[(size_t)i0 * 16 + c16];
            uint2 u1 = yp[(size_t)i1 * 16 + c16];
            uint2 u2 = yp[(size_t)i2 * 16 + c16];
            uint2 u3 = yp[(size_t)i3 * 16 + c16];
            a0 = hadd2u(a0, u0.x); a1 = hadd2u(a1, u0.y);
            a0 = hadd2u(a0, u1.x); a1 = hadd2u(a1, u1.y);
            a0 = hadd2u(a0, u2.x); a1 = hadd2u(a1, u2.y);
            a0 = hadd2u(a0, u3.x); a1 = hadd2u(a1, u3.y);
        }
        // tail: rem < 16, straight-line predicated (loads stay in flight)
        {
            uint2 z = make_uint2(0u, 0u);
            uint2 u0 = z, u1 = z, u2 = z, u3 = z;
            if (base + e4 < end)      u0 = yp[(size_t)col_idx[base + e4] * 16 + c16];
            if (base + 4 + e4 < end)  u1 = yp[(size_t)col_idx[base + 4 + e4] * 16 + c16];
            if (base + 8 + e4 < end)  u2 = yp[(size_t)col_idx[base + 8 + e4] * 16 + c16];
            if (base + 12 + e4 < end) u3 = yp[(size_t)col_idx[base + 12 + e4] * 16 + c16];
            a0 = hadd2u(a0, u0.x); a1 = hadd2u(a1, u0.y);
            a0 = hadd2u(a0, u1.x); a1 = hadd2u(a1, u1.y);
            a0 = hadd2u(a0, u2.x); a1 = hadd2u(a1, u2.y);
            a0 = hadd2u(a0, u3.x); a1 = hadd2u(a1, u3.y);
        }

        // reduce across the 4 edge groups (lanes differing in bits 4,5)
        #pragma unroll
        for (int m = 16; m <= 32; m <<= 1) {
            a0 = hadd2u(a0, (unsigned)__shfl_xor((int)a0, m));
            a1 = hadd2u(a1, (unsigned)__shfl_xor((int)a1, m));
        }

        // bias + relu in packed fp16; publish to wave-private st
        a0 = relu2(hadd2u(a0, b1p0));
        a1 = relu2(hadd2u(a1, b1p1));
        if (e4 == 0)
            reinterpret_cast<uint2*>(stp[wid])[c16] = make_uint2(a0, a1);

        // GEMM2: u[lane] = b2[lane] + sum_k2 dot2(st2[k2], W2p[k2][lane])
        float u = b2v;
        const uint4* sp = reinterpret_cast<const uint4*>(stp[wid]);
        #pragma unroll
        for (int j = 0; j < 8; ++j) {
            uint4 q = sp[j];
            u = fdot2h(q.x, sW2p[(4 * j + 0) * 64 + lane], u);
            u = fdot2h(q.y, sW2p[(4 * j + 1) * 64 + lane], u);
            u = fdot2h(q.z, sW2p[(4 * j + 2) * 64 + lane], u);
            u = fdot2h(q.w, sW2p[(4 * j + 3) * 64 + lane], u);
        }
        if (relu_out) u = fmaxf(u, 0.0f);
        h[(size_t)node * 64 + lane] = u;
    }
}

// ---------------- pooling: segment mean (batch is sorted) ----------------
// wave per 64-node chunk; batch ids shfl-broadcast; 8 row-loads in flight.

__global__ __launch_bounds__(256) void pool_kernel(const float* __restrict__ h,
                                                   const int* __restrict__ batch,
                                                   float* __restrict__ pool,
                                                   float* __restrict__ counts, int n) {
    int gwave = (blockIdx.x * 256 + threadIdx.x) >> 6;
    int lane  = threadIdx.x & 63;
    int s = gwave * 64;
    if (s >= n) return;
    int nhere = min(64, n - s);

    int bv = (s + lane < n) ? batch[s + lane] : -1;
    int cur = __shfl(bv, 0);
    float acc = 0.0f, cnt = 0.0f;

    #pragma unroll 1
    for (int i0 = 0; i0 < 64; i0 += 8) {
        float v[8];
        #pragma unroll
        for (int j = 0; j < 8; ++j) {
            int i = i0 + j;
            v[j] = (i < nhere) ? h[(size_t)(s + i) * 64 + lane] : 0.0f;
        }
        #pragma unroll
        for (int j = 0; j < 8; ++j) {
            int i = i0 + j;
            if (i < nhere) {
                int g = __shfl(bv, i);
                if (g != cur) {   // wave-uniform, rare
                    atomicAdd(&pool[cur * 64 + lane], acc);
                    if (lane == 0) atomicAdd(&counts[cur], cnt);
                    cur = g; acc = 0.0f; cnt = 0.0f;
                }
                acc += v[j];
                cnt += 1.0f;
            }
        }
    }
    atomicAdd(&pool[cur * 64 + lane], acc);
    if (lane == 0) atomicAdd(&counts[cur], cnt);
}

// ---------------- head: pooled @ fc1 + b, @ pred + b, sigmoid ----------------

__global__ void head_kernel(const float* __restrict__ pool, const float* __restrict__ counts,
                            const float* __restrict__ fc1_W, const float* __restrict__ fc1_b,
                            const float* __restrict__ pred_W, const float* __restrict__ pred_b,
                            float* __restrict__ out) {
    int g = blockIdx.x;
    int t = threadIdx.x;  // 64 threads; lanes >= 32 idle for the dot
    float s = 0.0f;
    if (t < 32) {
        float cnt = fmaxf(counts[g], 1.0f);
        float inv = 1.0f / cnt;
        float f = fc1_b[t];
        #pragma unroll
        for (int k = 0; k < 64; ++k)
            f = fmaf(pool[g * 64 + k] * inv, fc1_W[k * 32 + t], f);
        s = f * pred_W[t];
    }
    #pragma unroll
    for (int off = 32; off > 0; off >>= 1) s += __shfl_down(s, off);
    if (t == 0) out[g] = 1.0f / (1.0f + expf(-(s + pred_b[0])));
}

// ---------------- launch ----------------

extern "C" void kernel_launch(void* const* d_in, const int* in_sizes, int n_in,
                              void* d_out, int out_size, void* d_ws, size_t ws_size,
                              hipStream_t stream) {
    const float* x      = (const float*)d_in[0];
    const int*   e_src  = (const int*)d_in[1];               // edge_index[0]
    const int*   e_dst  = ((const int*)d_in[1]) + N_EDGES;   // edge_index[1]
    const int*   batch  = (const int*)d_in[2];
    const float* c1_W1 = (const float*)d_in[3];
    const float* c1_b1 = (const float*)d_in[4];
    const float* c1_W2 = (const float*)d_in[5];
    const float* c1_b2 = (const float*)d_in[6];
    const float* c2_W1 = (const float*)d_in[7];
    const float* c2_b1 = (const float*)d_in[8];
    const float* c2_W2 = (const float*)d_in[9];
    const float* c2_b2 = (const float*)d_in[10];
    const float* c3_W1 = (const float*)d_in[11];
    const float* c3_b1 = (const float*)d_in[12];
    const float* c3_W2 = (const float*)d_in[13];
    const float* c3_b2 = (const float*)d_in[14];
    const float* fc1_W = (const float*)d_in[15];
    const float* fc1_b = (const float*)d_in[16];
    const float* predW = (const float*)d_in[17];
    const float* predb = (const float*)d_in[18];
    float* out = (float*)d_out;

    // workspace carve-up (aligned to 256B)
    char* ws = (char*)d_ws;
    size_t off = 0;
    auto carve = [&](size_t bytes) {
        char* p = ws + off;
        off += (bytes + 255) & ~(size_t)255;
        return p;
    };
    ushort* y       = (ushort*)carve((size_t)N_NODES * 64 * 2);   // fp16 payload, 12.8 MB
    float* h        = (float*)carve((size_t)N_NODES * 64 * 4);
    int*   row_ptr  = (int*)carve(((size_t)N_NODES + 1) * 4);
    int*   col_idx  = (int*)carve((size_t)N_EDGES * 4);
    int*   bucketCnt = (int*)carve(NB * 4);
    int*   bucketOff = (int*)carve((NB + 1) * 4);
    int*   bucketCur = (int*)carve(NB * 4);
    float* pool     = (float*)carve(N_GRAPHS * 64 * 4);
    float* counts   = (float*)carve(N_GRAPHS * 4);
    // sorted edge array (12.8MB) aliases y: dead before the first project writes y
    uint2* sorted = (uint2*)y;
    (void)ws_size; (void)n_in; (void)in_sizes; (void)out_size;

    const int GIN_BLOCKS  = (N_NODES + NPB - 1) / NPB; // 6250 (16 nodes/block)
    const int PROJ_BLOCKS = (N_NODES + 63) / 64;       // 1563 (64 nodes/block)
    const int POOL_BLOCKS = (N_NODES + 255) / 256;     // 391 (4 waves x 64 nodes)

    // zero accumulators
    hipMemsetAsync(bucketCnt, 0, NB * 4, stream);
    hipMemsetAsync(pool, 0, (N_GRAPHS * 64 + N_GRAPHS) * 4 + 256, stream);

    // CSR build via bucket semi-sort (reused for all 3 layers)
    bucket_count<<<P12_BLOCKS, 256, 0, stream>>>(e_dst, bucketCnt, N_EDGES);
    bucket_scan<<<1, 256, 0, stream>>>(bucketCnt, bucketOff, bucketCur, row_ptr);
    bucket_scatter<<<P12_BLOCKS, 256, 0, stream>>>(e_src, e_dst, bucketCur, sorted, N_EDGES);
    bucket_csr<<<NB, 256, 0, stream>>>(sorted, bucketOff, row_ptr, col_idx);

    // layer 1 (project 128->64 BEFORE aggregation: linearity of W1)
    project_kernel<EMB><<<PROJ_BLOCKS, 256, 0, stream>>>(x, c1_W1, y);
    gin_layer<<<GIN_BLOCKS, 256, 0, stream>>>(y, row_ptr, col_idx, c1_b1, c1_W2, c1_b2, h, 1);

    // layer 2
    project_kernel<HID><<<PROJ_BLOCKS, 256, 0, stream>>>(h, c2_W1, y);
    gin_layer<<<GIN_BLOCKS, 256, 0, stream>>>(y, row_ptr, col_idx, c2_b1, c2_W2, c2_b2, h, 1);

    // layer 3 (no output relu)
    project_kernel<HID><<<PROJ_BLOCKS, 256, 0, stream>>>(h, c3_W1, y);
    gin_layer<<<GIN_BLOCKS, 256, 0, stream>>>(y, row_ptr, col_idx, c3_b1, c3_W2, c3_b2, h, 0);

    // pool + head
    pool_kernel<<<POOL_BLOCKS, 256, 0, stream>>>(h, batch, pool, counts, N_NODES);
    head_kernel<<<N_GRAPHS, 64, 0, stream>>>(pool, counts, fc1_W, fc1_b, predW, predb, out);
}